// Round 8
// baseline (992.816 us; speedup 1.0000x reference)
//
#include <hip/hip_runtime.h>
#include <stdint.h>

#define NN 50000
#define NE 800000
#define NG 512
#define H  128

typedef __attribute__((ext_vector_type(8))) short short8;
typedef __attribute__((ext_vector_type(16))) float f32x16;

union U4S8 { uint4 u; short8 s; };

__device__ __forceinline__ float softplusf(float x){
    return fmaxf(x, 0.f) + log1pf(expf(-fabsf(x)));
}

// split two fp32 into bf16-hi dword and bf16-lo dword (truncation split; residual ~2^-16)
__device__ __forceinline__ void split_pack(float x0, float x1, unsigned &hi, unsigned &lo){
    unsigned u0 = __float_as_uint(x0), u1 = __float_as_uint(x1);
    unsigned h0 = u0 & 0xffff0000u,  h1 = u1 & 0xffff0000u;
    hi = (h0 >> 16) | h1;
    float l0 = x0 - __uint_as_float(h0);
    float l1 = x1 - __uint_as_float(h1);
    lo = (__float_as_uint(l0) >> 16) | (__float_as_uint(l1) & 0xffff0000u);
}

// ---------------- sentinel writer ----------------
__global__ void k_sentinel(float* out, float val){
    int i = blockIdx.x*256 + threadIdx.x;
    if (i < 6*NG) out[i] = val;
}

// ---------------- W pre-split into MFMA B-fragment order ----------------
// wf layout: [mat(8)][hl(2)][ntg(4)][ks(8)][lane(64)] x 16B.  mat = layer*2 + phase.
// B-frag (32x32x16): lane holds B[k = ks*16 + (lane>>5)*8 + j][n = ntg*32 + (lane&31)], j=0..7.
__global__ __launch_bounds__(64) void k_wsplit(const float* __restrict__ gW1,
    const float* __restrict__ gW2, uint4* __restrict__ wf)
{
    int bid = blockIdx.x, lane = threadIdx.x;
    int mat = bid >> 5, ntg = (bid >> 3) & 3, ks = bid & 7;
    int l = mat >> 1;
    const float* W = (mat & 1) ? (gW2 + (size_t)l*H*H) : (gW1 + (size_t)l*H*H);
    int n  = ntg*32 + (lane & 31);
    int kb = ks*16 + (lane >> 5)*8;
    unsigned hi[4], lo[4];
#pragma unroll
    for (int d=0; d<4; d++){
        float x0 = W[(size_t)(kb + 2*d    )*H + n];
        float x1 = W[(size_t)(kb + 2*d + 1)*H + n];
        split_pack(x0, x1, hi[d], lo[d]);
    }
    int bh = ((mat*2 + 0)*4 + ntg)*8 + ks;
    int bl = ((mat*2 + 1)*4 + ntg)*8 + ks;
    wf[bh*64 + lane] = make_uint4(hi[0],hi[1],hi[2],hi[3]);
    wf[bl*64 + lane] = make_uint4(lo[0],lo[1],lo[2],lo[3]);
}

// ---------------- fused GIN MLP via bf16x2-split MFMA ----------------
// Block: 256 thr = 4 waves; tile 64 rows x 128 cols; wave w: row-tile (w&1), col-pair (w>>1).
// Per wave: 2 col-tiles of 32x32, acc = 2 x f32x16.  K-loop 8 steps of 16.
// A from global (fp32 -> split on the fly).  B pre-split in wf (held in VGPRs, half-K chunks).
// T = relu(X@W1+b1) written back into hx (input buffer; dead after phase-1 reads).
__global__ __launch_bounds__(256) void k_gin_mfma(float* __restrict__ hx,
    const float* __restrict__ b1, const float* __restrict__ b2,
    const uint4* __restrict__ wf, float* __restrict__ xout, int l, int relu2)
{
    const int t = threadIdx.x, lane = t & 63, w = t >> 6;
    const int rt = w & 1, cp = w >> 1;
    const int mb = blockIdx.x * 64;
    const int q  = lane >> 5;            // k-half selector within frag
    const int c31 = lane & 31;
    const int m  = mb + 32*rt + c31;     // A-row this lane loads
    const int m_eff = (m < NN) ? m : (NN-1);

    for (int ph = 0; ph < 2; ph++){
        const int mat = l*2 + ph;
        f32x16 acc0, acc1;
#pragma unroll
        for (int i=0;i<16;i++){ acc0[i] = 0.f; acc1[i] = 0.f; }

        uint4 B[2][4][2];   // [nt][kk][hl]
        for (int ks = 0; ks < 8; ks++){
            if ((ks & 3) == 0){
                int kh = ks >> 2;
#pragma unroll
                for (int nt=0; nt<2; nt++)
#pragma unroll
                  for (int kk=0; kk<4; kk++)
#pragma unroll
                    for (int hl=0; hl<2; hl++){
                        int ntg = 2*cp + nt;
                        int idx = (((mat*2 + hl)*4 + ntg)*8 + (kh*4 + kk))*64 + lane;
                        B[nt][kk][hl] = wf[idx];
                    }
            }
            const float* ap = hx + (size_t)m_eff*H + ks*16 + q*8;
            float4 a0 = *(const float4*)ap;
            float4 a1 = *(const float4*)(ap + 4);
            U4S8 Ahi, Alo;
            split_pack(a0.x, a0.y, Ahi.u.x, Alo.u.x);
            split_pack(a0.z, a0.w, Ahi.u.y, Alo.u.y);
            split_pack(a1.x, a1.y, Ahi.u.z, Alo.u.z);
            split_pack(a1.z, a1.w, Ahi.u.w, Alo.u.w);
            int kk = ks & 3;
            U4S8 bh0, bl0, bh1, bl1;
            bh0.u = B[0][kk][0]; bl0.u = B[0][kk][1];
            bh1.u = B[1][kk][0]; bl1.u = B[1][kk][1];
            acc0 = __builtin_amdgcn_mfma_f32_32x32x16_bf16(Ahi.s, bh0.s, acc0, 0,0,0);
            acc0 = __builtin_amdgcn_mfma_f32_32x32x16_bf16(Ahi.s, bl0.s, acc0, 0,0,0);
            acc0 = __builtin_amdgcn_mfma_f32_32x32x16_bf16(Alo.s, bh0.s, acc0, 0,0,0);
            acc1 = __builtin_amdgcn_mfma_f32_32x32x16_bf16(Ahi.s, bh1.s, acc1, 0,0,0);
            acc1 = __builtin_amdgcn_mfma_f32_32x32x16_bf16(Ahi.s, bl1.s, acc1, 0,0,0);
            acc1 = __builtin_amdgcn_mfma_f32_32x32x16_bf16(Alo.s, bh1.s, acc1, 0,0,0);
        }

        const float* bias = ph ? b2 : b1;
        float bv0 = bias[64*cp      + c31];
        float bv1 = bias[64*cp + 32 + c31];

        if (ph == 0){
            __syncthreads();    // all waves done reading hx before overwrite with T
#pragma unroll
            for (int reg=0; reg<16; reg++){
                int row = (reg & 3) + 8*(reg >> 2) + 4*q;    // D: row = (reg&3)+8(reg>>2)+4(lane>>5)
                int mm  = mb + 32*rt + row;
                if (mm < NN){
                    float v0 = fmaxf(acc0[reg] + bv0, 0.f);
                    float v1 = fmaxf(acc1[reg] + bv1, 0.f);
                    hx[(size_t)mm*H + 64*cp      + c31] = v0;
                    hx[(size_t)mm*H + 64*cp + 32 + c31] = v1;
                }
            }
            __threadfence();    // flush stores + invalidate L1 so phase-2 reads are fresh
            __syncthreads();
        } else {
#pragma unroll
            for (int reg=0; reg<16; reg++){
                int row = (reg & 3) + 8*(reg >> 2) + 4*q;
                int mm  = mb + 32*rt + row;
                if (mm < NN){
                    float v0 = acc0[reg] + bv0;
                    float v1 = acc1[reg] + bv1;
                    if (relu2){ v0 = fmaxf(v0, 0.f); v1 = fmaxf(v1, 0.f); }
                    xout[(size_t)mm*H + 64*cp      + c31] = v0;
                    xout[(size_t)mm*H + 64*cp + 32 + c31] = v1;
                }
            }
        }
    }
}

// ---------------- fused initial embedding GEMM (unchanged, round-7) ----------------
__global__ __launch_bounds__(256) void k_embed(const int* __restrict__ z,
    const float* __restrict__ pos, const float* __restrict__ emb,
    const float* __restrict__ Wp, const float* __restrict__ bp,
    const float* __restrict__ Wc, const float* __restrict__ bc,
    float* __restrict__ Y, int M)
{
    __shared__ float Xs[64*66];
    __shared__ float Ws[64*128];
    const int t  = threadIdx.x;
    const int tn = t & 15, tm = t >> 4;
    const int ca = tn*4, cb = 64 + tn*4;
    const int m0 = tm*4;
    const int mb = blockIdx.x*64;
    float acc[4][8];
#pragma unroll
    for (int i=0;i<4;i++)
#pragma unroll
      for (int j=0;j<8;j++) acc[i][j]=0.f;

    for (int k0=0; k0<256; k0+=64){
        {
            const int kq = t & 15, mr = t >> 4;
#pragma unroll
            for (int p=0;p<4;p++){
                int mm = mr + p*16;
                int gr = mb + mm;
                float4 v = make_float4(0.f,0.f,0.f,0.f);
                if (gr < M){
                    if (k0 < 128){
                        v = *(const float4*)(emb + (size_t)z[gr]*H + k0 + kq*4);
                    } else {
                        int c = (k0 - 128) + kq*4;
                        float4 w0 = *(const float4*)(Wp + c);
                        float4 w1 = *(const float4*)(Wp + H + c);
                        float4 w2 = *(const float4*)(Wp + 2*H + c);
                        float4 bb = *(const float4*)(bp + c);
                        float p0 = pos[gr*3+0], p1 = pos[gr*3+1], p2 = pos[gr*3+2];
                        v.x = p0*w0.x + p1*w1.x + p2*w2.x + bb.x;
                        v.y = p0*w0.y + p1*w1.y + p2*w2.y + bb.y;
                        v.z = p0*w0.z + p1*w1.z + p2*w2.z + bb.z;
                        v.w = p0*w0.w + p1*w1.w + p2*w2.w + bb.w;
                    }
                }
                float* d = &Xs[mm*66 + kq*4];
                d[0]=v.x; d[1]=v.y; d[2]=v.z; d[3]=v.w;
            }
        }
        {
            const int kk = t >> 2, c0 = (t & 3)*32;
            const float4* wr = (const float4*)(Wc + (size_t)(k0+kk)*H + c0);
            float4* d = (float4*)&Ws[kk*H + c0];
#pragma unroll
            for (int qq=0;qq<8;qq++) d[qq] = wr[qq];
        }
        __syncthreads();
#pragma unroll 8
        for (int kk=0; kk<64; kk++){
            float x0=Xs[(m0+0)*66+kk], x1=Xs[(m0+1)*66+kk];
            float x2=Xs[(m0+2)*66+kk], x3=Xs[(m0+3)*66+kk];
            float4 wa = *(const float4*)&Ws[kk*H + ca];
            float4 wb = *(const float4*)&Ws[kk*H + cb];
            float wv[8] = {wa.x,wa.y,wa.z,wa.w, wb.x,wb.y,wb.z,wb.w};
#pragma unroll
            for (int j=0;j<8;j++){
                acc[0][j] += x0*wv[j];
                acc[1][j] += x1*wv[j];
                acc[2][j] += x2*wv[j];
                acc[3][j] += x3*wv[j];
            }
        }
        __syncthreads();
    }
    float4 bvA = *(const float4*)(bc + ca);
    float4 bvB = *(const float4*)(bc + cb);
    float bv[8] = {bvA.x,bvA.y,bvA.z,bvA.w, bvB.x,bvB.y,bvB.z,bvB.w};
#pragma unroll
    for (int i=0;i<4;i++){
        int gr = mb + m0 + i;
        if (gr < M){
            float o[8];
#pragma unroll
            for (int j=0;j<8;j++) o[j] = fmaxf(acc[i][j] + bv[j], 0.f);
            *(float4*)(Y + (size_t)gr*H + ca) = make_float4(o[0],o[1],o[2],o[3]);
            *(float4*)(Y + (size_t)gr*H + cb) = make_float4(o[4],o[5],o[6],o[7]);
        }
    }
}

// ---------------- CSR build (by dst) ----------------
__global__ void k_zero(int* p, int n){ int i=blockIdx.x*256+threadIdx.x; if(i<n) p[i]=0; }

__global__ void k_count(const int* __restrict__ ei, int* __restrict__ cnt){
    int e = blockIdx.x*256+threadIdx.x;
    if (e < NE){ int d = ei[NE+e]; if ((unsigned)d < NN) atomicAdd(&cnt[d], 1); }
}

__global__ __launch_bounds__(256) void k_scan1(const int* __restrict__ cnt,
    int* __restrict__ iptr, int* __restrict__ bsum)
{
    __shared__ int s[256];
    int t = threadIdx.x, i = blockIdx.x*256 + t;
    int v = (i < NN) ? cnt[i] : 0;
    s[t] = v;
    for (int off=1; off<256; off<<=1){
        __syncthreads();
        int tv = (t >= off) ? s[t-off] : 0;
        __syncthreads();
        s[t] += tv;
    }
    __syncthreads();
    if (i < NN) iptr[i] = s[t] - v;
    if (t == 255) bsum[blockIdx.x] = s[255];
}

__global__ void k_scan2(int* bsum, int* iptr, int nb){
    if (threadIdx.x==0 && blockIdx.x==0){
        int run = 0;
        for (int b=0;b<nb;b++){ int v=bsum[b]; bsum[b]=run; run+=v; }
        iptr[NN] = run;
    }
}

__global__ void k_scan3(int* __restrict__ iptr, const int* __restrict__ bsum,
                        int* __restrict__ cur)
{
    int i = blockIdx.x*256 + threadIdx.x;
    if (i < NN){ int v = iptr[i] + bsum[i>>8]; iptr[i]=v; cur[i]=v; }
}

__global__ void k_scatter(const int* __restrict__ ei, int* __restrict__ cur,
                          int* __restrict__ esrc)
{
    int e = blockIdx.x*256 + threadIdx.x;
    if (e < NE){
        int d = ei[NE+e];
        if ((unsigned)d < NN){
            int p = atomicAdd(&cur[d], 1);
            if ((unsigned)p < NE) esrc[p] = ei[e];
        }
    }
}

// ---------------- GIN aggregation (unchanged, round-7) ----------------
__global__ __launch_bounds__(256) void k_agg(const float* __restrict__ x,
    const int* __restrict__ iptr, const int* __restrict__ esrc, float* __restrict__ h)
{
    int node = blockIdx.x*4 + (threadIdx.x >> 6);
    int lane = threadIdx.x & 63;
    int s = __builtin_amdgcn_readfirstlane(iptr[node]);
    int e = __builtin_amdgcn_readfirstlane(iptr[node+1]);
    const float2* __restrict__ xp = (const float2*)x;
    float2 acc = xp[(size_t)node*64 + lane];
    int j = s;
    for (; j+4 <= e; j += 4){
        int i0 = esrc[j+0], i1 = esrc[j+1], i2 = esrc[j+2], i3 = esrc[j+3];
        float2 v0 = xp[(size_t)i0*64 + lane];
        float2 v1 = xp[(size_t)i1*64 + lane];
        float2 v2 = xp[(size_t)i2*64 + lane];
        float2 v3 = xp[(size_t)i3*64 + lane];
        acc.x += (v0.x + v1.x) + (v2.x + v3.x);
        acc.y += (v0.y + v1.y) + (v2.y + v3.y);
    }
    for (; j < e; j++){
        int i0 = esrc[j];
        float2 v = xp[(size_t)i0*64 + lane];
        acc.x += v.x; acc.y += v.y;
    }
    ((float2*)h)[(size_t)node*64 + lane] = acc;
}

// ---------------- per-graph sum pooling ----------------
__global__ __launch_bounds__(128) void k_pool(const float* __restrict__ x,
    const int* __restrict__ batch, float* __restrict__ aggr)
{
    int g = blockIdx.x, c = threadIdx.x;
    int lo=0, hi=NN;
    while (lo<hi){ int mid=(lo+hi)>>1; if (batch[mid] < g) lo=mid+1; else hi=mid; }
    int s0 = lo;
    hi = NN;
    while (lo<hi){ int mid=(lo+hi)>>1; if (batch[mid] < g+1) lo=mid+1; else hi=mid; }
    int e0 = lo;
    float a0=0.f, a1=0.f, a2=0.f, a3=0.f;
    int i = s0;
    for (; i+4 <= e0; i += 4){
        a0 += x[(size_t)(i+0)*H + c];
        a1 += x[(size_t)(i+1)*H + c];
        a2 += x[(size_t)(i+2)*H + c];
        a3 += x[(size_t)(i+3)*H + c];
    }
    for (; i < e0; i++) a0 += x[(size_t)i*H + c];
    aggr[g*H + c] = (a0+a1) + (a2+a3);
}

// ---------------- 4 heads + evidential outputs (FP32 OUTPUT) ----------------
__global__ __launch_bounds__(128) void k_heads(const float* __restrict__ aggr,
    const float* __restrict__ W1, const float* __restrict__ b1,
    const float* __restrict__ W2, const float* __restrict__ b2,
    float* __restrict__ out)
{
    __shared__ float a[H];
    __shared__ float red[H];
    __shared__ float outk[4];
    int g = blockIdx.x, c = threadIdx.x;
    a[c] = aggr[g*H + c];
    __syncthreads();
    for (int k=0;k<4;k++){
        const float* w = W1 + k*H*H;
        float acc = b1[k*H + c];
#pragma unroll 4
        for (int qq=0;qq<H;qq++) acc += a[qq]*w[qq*H + c];
        red[c] = fmaxf(acc, 0.f) * W2[k*H + c];
        __syncthreads();
        for (int sd=64; sd>0; sd>>=1){
            if (c < sd) red[c] += red[c+sd];
            __syncthreads();
        }
        if (c==0) outk[k] = red[0] + b2[k];
        __syncthreads();
    }
    if (c==0){
        float o0=outk[0], o1=outk[1], o2=outk[2], o3=outk[3];
        float alpha = fmaxf(softplusf(o0) + 1.f, 1.f + 1e-4f);
        float beta  = softplusf(o1);
        float nu    = softplusf(o2);
        float am1   = alpha - 1.f;
        float aleat = beta / am1;
        float epis  = beta / (am1 * nu);
        out[0*NG+g] = o3;
        out[1*NG+g] = aleat;
        out[2*NG+g] = epis;
        out[3*NG+g] = nu;
        out[4*NG+g] = alpha;
        out[5*NG+g] = beta;
    }
}

extern "C" void kernel_launch(void* const* d_in, const int* in_sizes, int n_in,
                              void* d_out, int out_size, void* d_ws, size_t ws_size,
                              hipStream_t stream)
{
    const int*   z     = (const int*)d_in[0];
    const float* pos   = (const float*)d_in[1];
    const int*   batch = (const int*)d_in[2];
    const int*   eidx  = (const int*)d_in[3];
    const float* emb   = (const float*)d_in[4];
    const float* Wp    = (const float*)d_in[5];
    const float* bp    = (const float*)d_in[6];
    const float* Wc    = (const float*)d_in[7];
    const float* bc    = (const float*)d_in[8];
    const float* gW1   = (const float*)d_in[9];
    const float* gb1   = (const float*)d_in[10];
    const float* gW2   = (const float*)d_in[11];
    const float* gb2   = (const float*)d_in[12];
    const float* hW1   = (const float*)d_in[13];
    const float* hb1   = (const float*)d_in[14];
    const float* hW2   = (const float*)d_in[15];
    const float* hb2   = (const float*)d_in[16];
    float* out = (float*)d_out;

    bool ok_sizes = (n_in == 17)
        && in_sizes[0] == NN && in_sizes[1] == NN*3 && in_sizes[2] == NN
        && in_sizes[3] == 2*NE && in_sizes[4] == 100*H
        && in_sizes[7] == 2*H*H && in_sizes[9] == 4*H*H
        && in_sizes[13] == 4*H*H && in_sizes[16] == 4;
    if (!ok_sizes){ k_sentinel<<<12, 256, 0, stream>>>(out, 600000.0f); return; }

    const size_t OFF_X    = 256;
    const size_t OFF_H    = 25600256;
    const size_t OFF_AGGR = 51200256;
    const size_t OFF_IPTR = 51462400;
    const size_t OFF_CUR  = 51662592;
    const size_t OFF_ESRC = 51862784;
    const size_t OFF_BSUM = 55062784;
    const size_t OFF_WF   = 55063808;   // 8 mats x 2 hl x 4 ntg x 8 ks x 64 lanes x 16 B = 512 KB
    const size_t REQ      = 55588096;
    if (ws_size < REQ){ k_sentinel<<<12, 256, 0, stream>>>(out, 500000.0f); return; }

    char* ws = (char*)d_ws;
    float* x    = (float*)(ws + OFF_X);
    float* h    = (float*)(ws + OFF_H);
    float* aggr = (float*)(ws + OFF_AGGR);
    int*   iptr = (int*)(ws + OFF_IPTR);
    int*   cur  = (int*)(ws + OFF_CUR);
    int*   esrc = (int*)(ws + OFF_ESRC);
    int*   bsum = (int*)(ws + OFF_BSUM);
    uint4* wf   = (uint4*)(ws + OFF_WF);

    k_embed<<<(NN+63)/64, 256, 0, stream>>>(z, pos, emb, Wp, bp, Wc, bc, x, NN);

    // pre-split GIN weights into MFMA B-fragment order (bf16 hi/lo)
    k_wsplit<<<256, 64, 0, stream>>>(gW1, gW2, wf);

    k_zero<<<(NN+255)/256, 256, 0, stream>>>(cur, NN);
    k_count<<<(NE+255)/256, 256, 0, stream>>>(eidx, cur);
    k_scan1<<<196, 256, 0, stream>>>(cur, iptr, bsum);
    k_scan2<<<1, 64, 0, stream>>>(bsum, iptr, 196);
    k_scan3<<<196, 256, 0, stream>>>(iptr, bsum, cur);
    k_scatter<<<(NE+255)/256, 256, 0, stream>>>(eidx, cur, esrc);

    for (int l=0;l<4;l++){
        k_agg<<<NN/4, 256, 0, stream>>>(x, iptr, esrc, h);
        k_gin_mfma<<<(NN+63)/64, 256, 0, stream>>>(h,
            gb1 + (size_t)l*H, gb2 + (size_t)l*H, wf, x, l, (l<3)?1:0);
    }

    k_pool<<<NG, 128, 0, stream>>>(x, batch, aggr);
    k_heads<<<NG, 128, 0, stream>>>(aggr, hW1, hb1, hW2, hb2, out);
}

// Round 9
// 970.400 us; speedup vs baseline: 1.0231x; 1.0231x over previous
//
#include <hip/hip_runtime.h>
#include <stdint.h>

#define NN 50000
#define NE 800000
#define NG 512
#define H  128

typedef __attribute__((ext_vector_type(8))) short short8;
typedef __attribute__((ext_vector_type(16))) float f32x16;

union U4S8 { uint4 u; short8 s; };

__device__ __forceinline__ float softplusf(float x){
    return fmaxf(x, 0.f) + log1pf(expf(-fabsf(x)));
}

// round-to-nearest-even bf16 bits (high 16) of x
__device__ __forceinline__ unsigned rne_bf16_hi(float x){
    unsigned u = __float_as_uint(x);
    unsigned r = u + 0x7fffu + ((u >> 16) & 1u);
    return r & 0xffff0000u;
}

// split two fp32 into bf16-hi dword and bf16-lo dword (RNE split; residual ~2^-17)
__device__ __forceinline__ void split_pack(float x0, float x1, unsigned &hi, unsigned &lo){
    unsigned h0 = rne_bf16_hi(x0), h1 = rne_bf16_hi(x1);
    hi = (h0 >> 16) | h1;
    float l0 = x0 - __uint_as_float(h0);
    float l1 = x1 - __uint_as_float(h1);
    unsigned g0 = rne_bf16_hi(l0), g1 = rne_bf16_hi(l1);
    lo = (g0 >> 16) | g1;
}

// ---------------- sentinel writer ----------------
__global__ void k_sentinel(float* out, float val){
    int i = blockIdx.x*256 + threadIdx.x;
    if (i < 6*NG) out[i] = val;
}

// ---------------- W pre-split into MFMA B-fragment order ----------------
// wf layout: [mat(8)][hl(2)][ntg(4)][ks(8)][lane(64)] x 16B.  mat = layer*2 + phase.
// B-frag (32x32x16): lane holds B[k = ks*16 + (lane>>5)*8 + j][n = ntg*32 + (lane&31)], j=0..7.
__global__ __launch_bounds__(64) void k_wsplit(const float* __restrict__ gW1,
    const float* __restrict__ gW2, uint4* __restrict__ wf)
{
    int bid = blockIdx.x, lane = threadIdx.x;
    int mat = bid >> 5, ntg = (bid >> 3) & 3, ks = bid & 7;
    int l = mat >> 1;
    const float* W = (mat & 1) ? (gW2 + (size_t)l*H*H) : (gW1 + (size_t)l*H*H);
    int n  = ntg*32 + (lane & 31);
    int kb = ks*16 + (lane >> 5)*8;
    unsigned hi[4], lo[4];
#pragma unroll
    for (int d=0; d<4; d++){
        float x0 = W[(size_t)(kb + 2*d    )*H + n];
        float x1 = W[(size_t)(kb + 2*d + 1)*H + n];
        split_pack(x0, x1, hi[d], lo[d]);
    }
    int bh = ((mat*2 + 0)*4 + ntg)*8 + ks;
    int bl = ((mat*2 + 1)*4 + ntg)*8 + ks;
    wf[bh*64 + lane] = make_uint4(hi[0],hi[1],hi[2],hi[3]);
    wf[bl*64 + lane] = make_uint4(lo[0],lo[1],lo[2],lo[3]);
}

// ---------------- fused GIN MLP via bf16x2-split MFMA (fully static unroll) ----------------
// Block: 256 thr = 4 waves; tile 64 rows x 128 cols; wave w: row-tile (w&1), col-pair (w>>1).
// Per wave: 2 col-tiles of 32x32, acc = 2 x f32x16.  K = 2 chunks x 4 steps of 16 (all unrolled).
// B fragments live in VGPRs (static indexing only!).  T written back into hx.
__global__ __launch_bounds__(256) void k_gin_mfma(float* __restrict__ hx,
    const float* __restrict__ b1, const float* __restrict__ b2,
    const uint4* __restrict__ wf, float* __restrict__ xout, int l, int relu2)
{
    const int t = threadIdx.x, lane = t & 63, w = t >> 6;
    const int rt = w & 1, cp = w >> 1;
    const int mb = blockIdx.x * 64;
    const int q  = lane >> 5;
    const int c31 = lane & 31;
    const int m  = mb + 32*rt + c31;
    const int m_eff = (m < NN) ? m : (NN-1);

#pragma unroll
    for (int ph = 0; ph < 2; ph++){
        const int mat = l*2 + ph;
        f32x16 acc0, acc1;
#pragma unroll
        for (int i=0;i<16;i++){ acc0[i] = 0.f; acc1[i] = 0.f; }

#pragma unroll
        for (int kh = 0; kh < 2; kh++){
            uint4 B[2][4][2];   // [nt][kk][hl] — all indices static after unroll
#pragma unroll
            for (int nt=0; nt<2; nt++)
#pragma unroll
              for (int kk=0; kk<4; kk++)
#pragma unroll
                for (int hl=0; hl<2; hl++){
                    int ntg = 2*cp + nt;
                    int idx = (((mat*2 + hl)*4 + ntg)*8 + (kh*4 + kk))*64 + lane;
                    B[nt][kk][hl] = wf[idx];
                }
#pragma unroll
            for (int kk=0; kk<4; kk++){
                int ks = kh*4 + kk;
                const float* ap = hx + (size_t)m_eff*H + ks*16 + q*8;
                float4 a0 = *(const float4*)ap;
                float4 a1 = *(const float4*)(ap + 4);
                U4S8 Ahi, Alo;
                split_pack(a0.x, a0.y, Ahi.u.x, Alo.u.x);
                split_pack(a0.z, a0.w, Ahi.u.y, Alo.u.y);
                split_pack(a1.x, a1.y, Ahi.u.z, Alo.u.z);
                split_pack(a1.z, a1.w, Ahi.u.w, Alo.u.w);
                U4S8 bh0, bl0, bh1, bl1;
                bh0.u = B[0][kk][0]; bl0.u = B[0][kk][1];
                bh1.u = B[1][kk][0]; bl1.u = B[1][kk][1];
                acc0 = __builtin_amdgcn_mfma_f32_32x32x16_bf16(Ahi.s, bh0.s, acc0, 0,0,0);
                acc0 = __builtin_amdgcn_mfma_f32_32x32x16_bf16(Ahi.s, bl0.s, acc0, 0,0,0);
                acc0 = __builtin_amdgcn_mfma_f32_32x32x16_bf16(Alo.s, bh0.s, acc0, 0,0,0);
                acc1 = __builtin_amdgcn_mfma_f32_32x32x16_bf16(Ahi.s, bh1.s, acc1, 0,0,0);
                acc1 = __builtin_amdgcn_mfma_f32_32x32x16_bf16(Ahi.s, bl1.s, acc1, 0,0,0);
                acc1 = __builtin_amdgcn_mfma_f32_32x32x16_bf16(Alo.s, bh1.s, acc1, 0,0,0);
            }
        }

        const float* bias = ph ? b2 : b1;
        float bv0 = bias[64*cp      + c31];
        float bv1 = bias[64*cp + 32 + c31];

        if (ph == 0){
            __syncthreads();    // all waves done reading hx before overwrite with T
#pragma unroll
            for (int reg=0; reg<16; reg++){
                int row = (reg & 3) + 8*(reg >> 2) + 4*q;
                int mm  = mb + 32*rt + row;
                if (mm < NN){
                    float v0 = fmaxf(acc0[reg] + bv0, 0.f);
                    float v1 = fmaxf(acc1[reg] + bv1, 0.f);
                    hx[(size_t)mm*H + 64*cp      + c31] = v0;
                    hx[(size_t)mm*H + 64*cp + 32 + c31] = v1;
                }
            }
            __threadfence();
            __syncthreads();
        } else {
#pragma unroll
            for (int reg=0; reg<16; reg++){
                int row = (reg & 3) + 8*(reg >> 2) + 4*q;
                int mm  = mb + 32*rt + row;
                if (mm < NN){
                    float v0 = acc0[reg] + bv0;
                    float v1 = acc1[reg] + bv1;
                    if (relu2){ v0 = fmaxf(v0, 0.f); v1 = fmaxf(v1, 0.f); }
                    xout[(size_t)mm*H + 64*cp      + c31] = v0;
                    xout[(size_t)mm*H + 64*cp + 32 + c31] = v1;
                }
            }
        }
    }
}

// ---------------- fused initial embedding GEMM (unchanged) ----------------
__global__ __launch_bounds__(256) void k_embed(const int* __restrict__ z,
    const float* __restrict__ pos, const float* __restrict__ emb,
    const float* __restrict__ Wp, const float* __restrict__ bp,
    const float* __restrict__ Wc, const float* __restrict__ bc,
    float* __restrict__ Y, int M)
{
    __shared__ float Xs[64*66];
    __shared__ float Ws[64*128];
    const int t  = threadIdx.x;
    const int tn = t & 15, tm = t >> 4;
    const int ca = tn*4, cb = 64 + tn*4;
    const int m0 = tm*4;
    const int mb = blockIdx.x*64;
    float acc[4][8];
#pragma unroll
    for (int i=0;i<4;i++)
#pragma unroll
      for (int j=0;j<8;j++) acc[i][j]=0.f;

    for (int k0=0; k0<256; k0+=64){
        {
            const int kq = t & 15, mr = t >> 4;
#pragma unroll
            for (int p=0;p<4;p++){
                int mm = mr + p*16;
                int gr = mb + mm;
                float4 v = make_float4(0.f,0.f,0.f,0.f);
                if (gr < M){
                    if (k0 < 128){
                        v = *(const float4*)(emb + (size_t)z[gr]*H + k0 + kq*4);
                    } else {
                        int c = (k0 - 128) + kq*4;
                        float4 w0 = *(const float4*)(Wp + c);
                        float4 w1 = *(const float4*)(Wp + H + c);
                        float4 w2 = *(const float4*)(Wp + 2*H + c);
                        float4 bb = *(const float4*)(bp + c);
                        float p0 = pos[gr*3+0], p1 = pos[gr*3+1], p2 = pos[gr*3+2];
                        v.x = p0*w0.x + p1*w1.x + p2*w2.x + bb.x;
                        v.y = p0*w0.y + p1*w1.y + p2*w2.y + bb.y;
                        v.z = p0*w0.z + p1*w1.z + p2*w2.z + bb.z;
                        v.w = p0*w0.w + p1*w1.w + p2*w2.w + bb.w;
                    }
                }
                float* d = &Xs[mm*66 + kq*4];
                d[0]=v.x; d[1]=v.y; d[2]=v.z; d[3]=v.w;
            }
        }
        {
            const int kk = t >> 2, c0 = (t & 3)*32;
            const float4* wr = (const float4*)(Wc + (size_t)(k0+kk)*H + c0);
            float4* d = (float4*)&Ws[kk*H + c0];
#pragma unroll
            for (int qq=0;qq<8;qq++) d[qq] = wr[qq];
        }
        __syncthreads();
#pragma unroll 8
        for (int kk=0; kk<64; kk++){
            float x0=Xs[(m0+0)*66+kk], x1=Xs[(m0+1)*66+kk];
            float x2=Xs[(m0+2)*66+kk], x3=Xs[(m0+3)*66+kk];
            float4 wa = *(const float4*)&Ws[kk*H + ca];
            float4 wb = *(const float4*)&Ws[kk*H + cb];
            float wv[8] = {wa.x,wa.y,wa.z,wa.w, wb.x,wb.y,wb.z,wb.w};
#pragma unroll
            for (int j=0;j<8;j++){
                acc[0][j] += x0*wv[j];
                acc[1][j] += x1*wv[j];
                acc[2][j] += x2*wv[j];
                acc[3][j] += x3*wv[j];
            }
        }
        __syncthreads();
    }
    float4 bvA = *(const float4*)(bc + ca);
    float4 bvB = *(const float4*)(bc + cb);
    float bv[8] = {bvA.x,bvA.y,bvA.z,bvA.w, bvB.x,bvB.y,bvB.z,bvB.w};
#pragma unroll
    for (int i=0;i<4;i++){
        int gr = mb + m0 + i;
        if (gr < M){
            float o[8];
#pragma unroll
            for (int j=0;j<8;j++) o[j] = fmaxf(acc[i][j] + bv[j], 0.f);
            *(float4*)(Y + (size_t)gr*H + ca) = make_float4(o[0],o[1],o[2],o[3]);
            *(float4*)(Y + (size_t)gr*H + cb) = make_float4(o[4],o[5],o[6],o[7]);
        }
    }
}

// ---------------- CSR build (by dst) ----------------
__global__ void k_zero(int* p, int n){ int i=blockIdx.x*256+threadIdx.x; if(i<n) p[i]=0; }

__global__ void k_count(const int* __restrict__ ei, int* __restrict__ cnt){
    int e = blockIdx.x*256+threadIdx.x;
    if (e < NE){ int d = ei[NE+e]; if ((unsigned)d < NN) atomicAdd(&cnt[d], 1); }
}

__global__ __launch_bounds__(256) void k_scan1(const int* __restrict__ cnt,
    int* __restrict__ iptr, int* __restrict__ bsum)
{
    __shared__ int s[256];
    int t = threadIdx.x, i = blockIdx.x*256 + t;
    int v = (i < NN) ? cnt[i] : 0;
    s[t] = v;
    for (int off=1; off<256; off<<=1){
        __syncthreads();
        int tv = (t >= off) ? s[t-off] : 0;
        __syncthreads();
        s[t] += tv;
    }
    __syncthreads();
    if (i < NN) iptr[i] = s[t] - v;
    if (t == 255) bsum[blockIdx.x] = s[255];
}

__global__ void k_scan2(int* bsum, int* iptr, int nb){
    if (threadIdx.x==0 && blockIdx.x==0){
        int run = 0;
        for (int b=0;b<nb;b++){ int v=bsum[b]; bsum[b]=run; run+=v; }
        iptr[NN] = run;
    }
}

__global__ void k_scan3(int* __restrict__ iptr, const int* __restrict__ bsum,
                        int* __restrict__ cur)
{
    int i = blockIdx.x*256 + threadIdx.x;
    if (i < NN){ int v = iptr[i] + bsum[i>>8]; iptr[i]=v; cur[i]=v; }
}

__global__ void k_scatter(const int* __restrict__ ei, int* __restrict__ cur,
                          int* __restrict__ esrc)
{
    int e = blockIdx.x*256 + threadIdx.x;
    if (e < NE){
        int d = ei[NE+e];
        if ((unsigned)d < NN){
            int p = atomicAdd(&cur[d], 1);
            if ((unsigned)p < NE) esrc[p] = ei[e];
        }
    }
}

// ---------------- GIN aggregation: wave-per-node, float2 lanes, 8-deep gather ----------------
__global__ __launch_bounds__(256) void k_agg(const float* __restrict__ x,
    const int* __restrict__ iptr, const int* __restrict__ esrc, float* __restrict__ h)
{
    int node = blockIdx.x*4 + (threadIdx.x >> 6);
    int lane = threadIdx.x & 63;
    int s = __builtin_amdgcn_readfirstlane(iptr[node]);
    int e = __builtin_amdgcn_readfirstlane(iptr[node+1]);
    const float2* __restrict__ xp = (const float2*)x;
    float2 acc = xp[(size_t)node*64 + lane];
    float2 accb = make_float2(0.f, 0.f);
    int j = s;
    for (; j+8 <= e; j += 8){
        int i0 = esrc[j+0], i1 = esrc[j+1], i2 = esrc[j+2], i3 = esrc[j+3];
        int i4 = esrc[j+4], i5 = esrc[j+5], i6 = esrc[j+6], i7 = esrc[j+7];
        float2 v0 = xp[(size_t)i0*64 + lane];
        float2 v1 = xp[(size_t)i1*64 + lane];
        float2 v2 = xp[(size_t)i2*64 + lane];
        float2 v3 = xp[(size_t)i3*64 + lane];
        float2 v4 = xp[(size_t)i4*64 + lane];
        float2 v5 = xp[(size_t)i5*64 + lane];
        float2 v6 = xp[(size_t)i6*64 + lane];
        float2 v7 = xp[(size_t)i7*64 + lane];
        acc.x  += (v0.x + v1.x) + (v2.x + v3.x);
        acc.y  += (v0.y + v1.y) + (v2.y + v3.y);
        accb.x += (v4.x + v5.x) + (v6.x + v7.x);
        accb.y += (v4.y + v5.y) + (v6.y + v7.y);
    }
    for (; j+4 <= e; j += 4){
        int i0 = esrc[j+0], i1 = esrc[j+1], i2 = esrc[j+2], i3 = esrc[j+3];
        float2 v0 = xp[(size_t)i0*64 + lane];
        float2 v1 = xp[(size_t)i1*64 + lane];
        float2 v2 = xp[(size_t)i2*64 + lane];
        float2 v3 = xp[(size_t)i3*64 + lane];
        acc.x += (v0.x + v1.x) + (v2.x + v3.x);
        acc.y += (v0.y + v1.y) + (v2.y + v3.y);
    }
    for (; j < e; j++){
        int i0 = esrc[j];
        float2 v = xp[(size_t)i0*64 + lane];
        acc.x += v.x; acc.y += v.y;
    }
    acc.x += accb.x; acc.y += accb.y;
    ((float2*)h)[(size_t)node*64 + lane] = acc;
}

// ---------------- per-graph sum pooling ----------------
__global__ __launch_bounds__(128) void k_pool(const float* __restrict__ x,
    const int* __restrict__ batch, float* __restrict__ aggr)
{
    int g = blockIdx.x, c = threadIdx.x;
    int lo=0, hi=NN;
    while (lo<hi){ int mid=(lo+hi)>>1; if (batch[mid] < g) lo=mid+1; else hi=mid; }
    int s0 = lo;
    hi = NN;
    while (lo<hi){ int mid=(lo+hi)>>1; if (batch[mid] < g+1) lo=mid+1; else hi=mid; }
    int e0 = lo;
    float a0=0.f, a1=0.f, a2=0.f, a3=0.f;
    int i = s0;
    for (; i+4 <= e0; i += 4){
        a0 += x[(size_t)(i+0)*H + c];
        a1 += x[(size_t)(i+1)*H + c];
        a2 += x[(size_t)(i+2)*H + c];
        a3 += x[(size_t)(i+3)*H + c];
    }
    for (; i < e0; i++) a0 += x[(size_t)i*H + c];
    aggr[g*H + c] = (a0+a1) + (a2+a3);
}

// ---------------- 4 heads + evidential outputs (FP32 OUTPUT) ----------------
__global__ __launch_bounds__(128) void k_heads(const float* __restrict__ aggr,
    const float* __restrict__ W1, const float* __restrict__ b1,
    const float* __restrict__ W2, const float* __restrict__ b2,
    float* __restrict__ out)
{
    __shared__ float a[H];
    __shared__ float red[H];
    __shared__ float outk[4];
    int g = blockIdx.x, c = threadIdx.x;
    a[c] = aggr[g*H + c];
    __syncthreads();
    for (int k=0;k<4;k++){
        const float* w = W1 + k*H*H;
        float acc = b1[k*H + c];
#pragma unroll 4
        for (int qq=0;qq<H;qq++) acc += a[qq]*w[qq*H + c];
        red[c] = fmaxf(acc, 0.f) * W2[k*H + c];
        __syncthreads();
        for (int sd=64; sd>0; sd>>=1){
            if (c < sd) red[c] += red[c+sd];
            __syncthreads();
        }
        if (c==0) outk[k] = red[0] + b2[k];
        __syncthreads();
    }
    if (c==0){
        float o0=outk[0], o1=outk[1], o2=outk[2], o3=outk[3];
        float alpha = fmaxf(softplusf(o0) + 1.f, 1.f + 1e-4f);
        float beta  = softplusf(o1);
        float nu    = softplusf(o2);
        float am1   = alpha - 1.f;
        float aleat = beta / am1;
        float epis  = beta / (am1 * nu);
        out[0*NG+g] = o3;
        out[1*NG+g] = aleat;
        out[2*NG+g] = epis;
        out[3*NG+g] = nu;
        out[4*NG+g] = alpha;
        out[5*NG+g] = beta;
    }
}

extern "C" void kernel_launch(void* const* d_in, const int* in_sizes, int n_in,
                              void* d_out, int out_size, void* d_ws, size_t ws_size,
                              hipStream_t stream)
{
    const int*   z     = (const int*)d_in[0];
    const float* pos   = (const float*)d_in[1];
    const int*   batch = (const int*)d_in[2];
    const int*   eidx  = (const int*)d_in[3];
    const float* emb   = (const float*)d_in[4];
    const float* Wp    = (const float*)d_in[5];
    const float* bp    = (const float*)d_in[6];
    const float* Wc    = (const float*)d_in[7];
    const float* bc    = (const float*)d_in[8];
    const float* gW1   = (const float*)d_in[9];
    const float* gb1   = (const float*)d_in[10];
    const float* gW2   = (const float*)d_in[11];
    const float* gb2   = (const float*)d_in[12];
    const float* hW1   = (const float*)d_in[13];
    const float* hb1   = (const float*)d_in[14];
    const float* hW2   = (const float*)d_in[15];
    const float* hb2   = (const float*)d_in[16];
    float* out = (float*)d_out;

    bool ok_sizes = (n_in == 17)
        && in_sizes[0] == NN && in_sizes[1] == NN*3 && in_sizes[2] == NN
        && in_sizes[3] == 2*NE && in_sizes[4] == 100*H
        && in_sizes[7] == 2*H*H && in_sizes[9] == 4*H*H
        && in_sizes[13] == 4*H*H && in_sizes[16] == 4;
    if (!ok_sizes){ k_sentinel<<<12, 256, 0, stream>>>(out, 600000.0f); return; }

    const size_t OFF_X    = 256;
    const size_t OFF_H    = 25600256;
    const size_t OFF_AGGR = 51200256;
    const size_t OFF_IPTR = 51462400;
    const size_t OFF_CUR  = 51662592;
    const size_t OFF_ESRC = 51862784;
    const size_t OFF_BSUM = 55062784;
    const size_t OFF_WF   = 55063808;   // 8 mats x 2 hl x 4 ntg x 8 ks x 64 lanes x 16 B = 512 KB
    const size_t REQ      = 55588096;
    if (ws_size < REQ){ k_sentinel<<<12, 256, 0, stream>>>(out, 500000.0f); return; }

    char* ws = (char*)d_ws;
    float* x    = (float*)(ws + OFF_X);
    float* h    = (float*)(ws + OFF_H);
    float* aggr = (float*)(ws + OFF_AGGR);
    int*   iptr = (int*)(ws + OFF_IPTR);
    int*   cur  = (int*)(ws + OFF_CUR);
    int*   esrc = (int*)(ws + OFF_ESRC);
    int*   bsum = (int*)(ws + OFF_BSUM);
    uint4* wf   = (uint4*)(ws + OFF_WF);

    k_embed<<<(NN+63)/64, 256, 0, stream>>>(z, pos, emb, Wp, bp, Wc, bc, x, NN);

    k_wsplit<<<256, 64, 0, stream>>>(gW1, gW2, wf);

    k_zero<<<(NN+255)/256, 256, 0, stream>>>(cur, NN);
    k_count<<<(NE+255)/256, 256, 0, stream>>>(eidx, cur);
    k_scan1<<<196, 256, 0, stream>>>(cur, iptr, bsum);
    k_scan2<<<1, 64, 0, stream>>>(bsum, iptr, 196);
    k_scan3<<<196, 256, 0, stream>>>(iptr, bsum, cur);
    k_scatter<<<(NE+255)/256, 256, 0, stream>>>(eidx, cur, esrc);

    for (int l=0;l<4;l++){
        k_agg<<<NN/4, 256, 0, stream>>>(x, iptr, esrc, h);
        k_gin_mfma<<<(NN+63)/64, 256, 0, stream>>>(h,
            gb1 + (size_t)l*H, gb2 + (size_t)l*H, wf, x, l, (l<3)?1:0);
    }

    k_pool<<<NG, 128, 0, stream>>>(x, batch, aggr);
    k_heads<<<NG, 128, 0, stream>>>(aggr, hW1, hb1, hW2, hb2, out);
}

// Round 10
// 966.909 us; speedup vs baseline: 1.0268x; 1.0036x over previous
//
#include <hip/hip_runtime.h>
#include <stdint.h>

#define NN 50000
#define NE 800000
#define NG 512
#define H  128

typedef __attribute__((ext_vector_type(8))) short short8;
typedef __attribute__((ext_vector_type(16))) float f32x16;

union U4S8 { uint4 u; short8 s; };

__device__ __forceinline__ float softplusf(float x){
    return fmaxf(x, 0.f) + log1pf(expf(-fabsf(x)));
}

// round-to-nearest-even bf16 bits (high 16) of x
__device__ __forceinline__ unsigned rne_bf16_hi(float x){
    unsigned u = __float_as_uint(x);
    unsigned r = u + 0x7fffu + ((u >> 16) & 1u);
    return r & 0xffff0000u;
}

// split two fp32 into bf16-hi dword and bf16-lo dword (RNE split; residual ~2^-17)
__device__ __forceinline__ void split_pack(float x0, float x1, unsigned &hi, unsigned &lo){
    unsigned h0 = rne_bf16_hi(x0), h1 = rne_bf16_hi(x1);
    hi = (h0 >> 16) | h1;
    float l0 = x0 - __uint_as_float(h0);
    float l1 = x1 - __uint_as_float(h1);
    unsigned g0 = rne_bf16_hi(l0), g1 = rne_bf16_hi(l1);
    lo = (g0 >> 16) | g1;
}

// ---------------- sentinel writer ----------------
__global__ void k_sentinel(float* out, float val){
    int i = blockIdx.x*256 + threadIdx.x;
    if (i < 6*NG) out[i] = val;
}

// ---------------- W pre-split into MFMA B-fragment order ----------------
// wf layout: [mat(8)][hl(2)][ntg(4)][ks(8)][lane(64)] x 16B.  mat = layer*2 + phase.
// B-frag (32x32x16): lane holds B[k = ks*16 + (lane>>5)*8 + j][n = ntg*32 + (lane&31)], j=0..7.
__global__ __launch_bounds__(64) void k_wsplit(const float* __restrict__ gW1,
    const float* __restrict__ gW2, uint4* __restrict__ wf)
{
    int bid = blockIdx.x, lane = threadIdx.x;
    int mat = bid >> 5, ntg = (bid >> 3) & 3, ks = bid & 7;
    int l = mat >> 1;
    const float* W = (mat & 1) ? (gW2 + (size_t)l*H*H) : (gW1 + (size_t)l*H*H);
    int n  = ntg*32 + (lane & 31);
    int kb = ks*16 + (lane >> 5)*8;
    unsigned hi[4], lo[4];
#pragma unroll
    for (int d=0; d<4; d++){
        float x0 = W[(size_t)(kb + 2*d    )*H + n];
        float x1 = W[(size_t)(kb + 2*d + 1)*H + n];
        split_pack(x0, x1, hi[d], lo[d]);
    }
    int bh = ((mat*2 + 0)*4 + ntg)*8 + ks;
    int bl = ((mat*2 + 1)*4 + ntg)*8 + ks;
    wf[bh*64 + lane] = make_uint4(hi[0],hi[1],hi[2],hi[3]);
    wf[bl*64 + lane] = make_uint4(lo[0],lo[1],lo[2],lo[3]);
}

// ---------------- fused GIN MLP via bf16x2-split MFMA (full-phase load hoist) ----------------
// Block: 256 thr = 4 waves; tile 64 rows x 128 cols; wave w: row-tile (w&1), col-pair (w>>1).
// Per phase: ALL loads hoisted first (B: 32 uint4, A: 16 float4 => ~48 loads in flight),
// then the fully-unrolled split+MFMA chain.  __launch_bounds__(256,2) gives the VGPR room.
__global__ __launch_bounds__(256, 2) void k_gin_mfma(float* __restrict__ hx,
    const float* __restrict__ b1, const float* __restrict__ b2,
    const uint4* __restrict__ wf, float* __restrict__ xout, int l, int relu2)
{
    const int t = threadIdx.x, lane = t & 63, w = t >> 6;
    const int rt = w & 1, cp = w >> 1;
    const int mb = blockIdx.x * 64;
    const int q  = lane >> 5;
    const int c31 = lane & 31;
    const int m  = mb + 32*rt + c31;
    const int m_eff = (m < NN) ? m : (NN-1);

#pragma unroll
    for (int ph = 0; ph < 2; ph++){
        const int mat = l*2 + ph;

        // ---- hoist ALL B loads for this phase (32 x uint4) ----
        uint4 B[2][2][4][2];   // [kh][nt][kk][hl] — static indices only
#pragma unroll
        for (int kh=0; kh<2; kh++)
#pragma unroll
          for (int nt=0; nt<2; nt++)
#pragma unroll
            for (int kk=0; kk<4; kk++)
#pragma unroll
              for (int hl=0; hl<2; hl++){
                  int ntg = 2*cp + nt;
                  int idx = (((mat*2 + hl)*4 + ntg)*8 + (kh*4 + kk))*64 + lane;
                  B[kh][nt][kk][hl] = wf[idx];
              }

        // ---- hoist ALL A loads for this phase (16 x float4) ----
        float4 A[8][2];
#pragma unroll
        for (int ks=0; ks<8; ks++){
            const float* ap = hx + (size_t)m_eff*H + ks*16 + q*8;
            A[ks][0] = *(const float4*)ap;
            A[ks][1] = *(const float4*)(ap + 4);
        }

        f32x16 acc0, acc1;
#pragma unroll
        for (int i=0;i<16;i++){ acc0[i] = 0.f; acc1[i] = 0.f; }

        // ---- compute: split + MFMA, fully unrolled ----
#pragma unroll
        for (int ks=0; ks<8; ks++){
            const int kh = ks >> 2, kk = ks & 3;
            float4 a0 = A[ks][0], a1 = A[ks][1];
            U4S8 Ahi, Alo;
            split_pack(a0.x, a0.y, Ahi.u.x, Alo.u.x);
            split_pack(a0.z, a0.w, Ahi.u.y, Alo.u.y);
            split_pack(a1.x, a1.y, Ahi.u.z, Alo.u.z);
            split_pack(a1.z, a1.w, Ahi.u.w, Alo.u.w);
            U4S8 bh0, bl0, bh1, bl1;
            bh0.u = B[kh][0][kk][0]; bl0.u = B[kh][0][kk][1];
            bh1.u = B[kh][1][kk][0]; bl1.u = B[kh][1][kk][1];
            acc0 = __builtin_amdgcn_mfma_f32_32x32x16_bf16(Ahi.s, bh0.s, acc0, 0,0,0);
            acc0 = __builtin_amdgcn_mfma_f32_32x32x16_bf16(Ahi.s, bl0.s, acc0, 0,0,0);
            acc0 = __builtin_amdgcn_mfma_f32_32x32x16_bf16(Alo.s, bh0.s, acc0, 0,0,0);
            acc1 = __builtin_amdgcn_mfma_f32_32x32x16_bf16(Ahi.s, bh1.s, acc1, 0,0,0);
            acc1 = __builtin_amdgcn_mfma_f32_32x32x16_bf16(Ahi.s, bl1.s, acc1, 0,0,0);
            acc1 = __builtin_amdgcn_mfma_f32_32x32x16_bf16(Alo.s, bh1.s, acc1, 0,0,0);
        }

        const float* bias = ph ? b2 : b1;
        float bv0 = bias[64*cp      + c31];
        float bv1 = bias[64*cp + 32 + c31];

        if (ph == 0){
            __syncthreads();    // all waves done reading hx before overwrite with T
#pragma unroll
            for (int reg=0; reg<16; reg++){
                int row = (reg & 3) + 8*(reg >> 2) + 4*q;
                int mm  = mb + 32*rt + row;
                if (mm < NN){
                    float v0 = fmaxf(acc0[reg] + bv0, 0.f);
                    float v1 = fmaxf(acc1[reg] + bv1, 0.f);
                    hx[(size_t)mm*H + 64*cp      + c31] = v0;
                    hx[(size_t)mm*H + 64*cp + 32 + c31] = v1;
                }
            }
            __threadfence();
            __syncthreads();
        } else {
#pragma unroll
            for (int reg=0; reg<16; reg++){
                int row = (reg & 3) + 8*(reg >> 2) + 4*q;
                int mm  = mb + 32*rt + row;
                if (mm < NN){
                    float v0 = acc0[reg] + bv0;
                    float v1 = acc1[reg] + bv1;
                    if (relu2){ v0 = fmaxf(v0, 0.f); v1 = fmaxf(v1, 0.f); }
                    xout[(size_t)mm*H + 64*cp      + c31] = v0;
                    xout[(size_t)mm*H + 64*cp + 32 + c31] = v1;
                }
            }
        }
    }
}

// ---------------- fused initial embedding GEMM (unchanged) ----------------
__global__ __launch_bounds__(256) void k_embed(const int* __restrict__ z,
    const float* __restrict__ pos, const float* __restrict__ emb,
    const float* __restrict__ Wp, const float* __restrict__ bp,
    const float* __restrict__ Wc, const float* __restrict__ bc,
    float* __restrict__ Y, int M)
{
    __shared__ float Xs[64*66];
    __shared__ float Ws[64*128];
    const int t  = threadIdx.x;
    const int tn = t & 15, tm = t >> 4;
    const int ca = tn*4, cb = 64 + tn*4;
    const int m0 = tm*4;
    const int mb = blockIdx.x*64;
    float acc[4][8];
#pragma unroll
    for (int i=0;i<4;i++)
#pragma unroll
      for (int j=0;j<8;j++) acc[i][j]=0.f;

    for (int k0=0; k0<256; k0+=64){
        {
            const int kq = t & 15, mr = t >> 4;
#pragma unroll
            for (int p=0;p<4;p++){
                int mm = mr + p*16;
                int gr = mb + mm;
                float4 v = make_float4(0.f,0.f,0.f,0.f);
                if (gr < M){
                    if (k0 < 128){
                        v = *(const float4*)(emb + (size_t)z[gr]*H + k0 + kq*4);
                    } else {
                        int c = (k0 - 128) + kq*4;
                        float4 w0 = *(const float4*)(Wp + c);
                        float4 w1 = *(const float4*)(Wp + H + c);
                        float4 w2 = *(const float4*)(Wp + 2*H + c);
                        float4 bb = *(const float4*)(bp + c);
                        float p0 = pos[gr*3+0], p1 = pos[gr*3+1], p2 = pos[gr*3+2];
                        v.x = p0*w0.x + p1*w1.x + p2*w2.x + bb.x;
                        v.y = p0*w0.y + p1*w1.y + p2*w2.y + bb.y;
                        v.z = p0*w0.z + p1*w1.z + p2*w2.z + bb.z;
                        v.w = p0*w0.w + p1*w1.w + p2*w2.w + bb.w;
                    }
                }
                float* d = &Xs[mm*66 + kq*4];
                d[0]=v.x; d[1]=v.y; d[2]=v.z; d[3]=v.w;
            }
        }
        {
            const int kk = t >> 2, c0 = (t & 3)*32;
            const float4* wr = (const float4*)(Wc + (size_t)(k0+kk)*H + c0);
            float4* d = (float4*)&Ws[kk*H + c0];
#pragma unroll
            for (int qq=0;qq<8;qq++) d[qq] = wr[qq];
        }
        __syncthreads();
#pragma unroll 8
        for (int kk=0; kk<64; kk++){
            float x0=Xs[(m0+0)*66+kk], x1=Xs[(m0+1)*66+kk];
            float x2=Xs[(m0+2)*66+kk], x3=Xs[(m0+3)*66+kk];
            float4 wa = *(const float4*)&Ws[kk*H + ca];
            float4 wb = *(const float4*)&Ws[kk*H + cb];
            float wv[8] = {wa.x,wa.y,wa.z,wa.w, wb.x,wb.y,wb.z,wb.w};
#pragma unroll
            for (int j=0;j<8;j++){
                acc[0][j] += x0*wv[j];
                acc[1][j] += x1*wv[j];
                acc[2][j] += x2*wv[j];
                acc[3][j] += x3*wv[j];
            }
        }
        __syncthreads();
    }
    float4 bvA = *(const float4*)(bc + ca);
    float4 bvB = *(const float4*)(bc + cb);
    float bv[8] = {bvA.x,bvA.y,bvA.z,bvA.w, bvB.x,bvB.y,bvB.z,bvB.w};
#pragma unroll
    for (int i=0;i<4;i++){
        int gr = mb + m0 + i;
        if (gr < M){
            float o[8];
#pragma unroll
            for (int j=0;j<8;j++) o[j] = fmaxf(acc[i][j] + bv[j], 0.f);
            *(float4*)(Y + (size_t)gr*H + ca) = make_float4(o[0],o[1],o[2],o[3]);
            *(float4*)(Y + (size_t)gr*H + cb) = make_float4(o[4],o[5],o[6],o[7]);
        }
    }
}

// ---------------- CSR build (by dst) ----------------
__global__ void k_zero(int* p, int n){ int i=blockIdx.x*256+threadIdx.x; if(i<n) p[i]=0; }

__global__ void k_count(const int* __restrict__ ei, int* __restrict__ cnt){
    int e = blockIdx.x*256+threadIdx.x;
    if (e < NE){ int d = ei[NE+e]; if ((unsigned)d < NN) atomicAdd(&cnt[d], 1); }
}

__global__ __launch_bounds__(256) void k_scan1(const int* __restrict__ cnt,
    int* __restrict__ iptr, int* __restrict__ bsum)
{
    __shared__ int s[256];
    int t = threadIdx.x, i = blockIdx.x*256 + t;
    int v = (i < NN) ? cnt[i] : 0;
    s[t] = v;
    for (int off=1; off<256; off<<=1){
        __syncthreads();
        int tv = (t >= off) ? s[t-off] : 0;
        __syncthreads();
        s[t] += tv;
    }
    __syncthreads();
    if (i < NN) iptr[i] = s[t] - v;
    if (t == 255) bsum[blockIdx.x] = s[255];
}

__global__ void k_scan2(int* bsum, int* iptr, int nb){
    if (threadIdx.x==0 && blockIdx.x==0){
        int run = 0;
        for (int b=0;b<nb;b++){ int v=bsum[b]; bsum[b]=run; run+=v; }
        iptr[NN] = run;
    }
}

__global__ void k_scan3(int* __restrict__ iptr, const int* __restrict__ bsum,
                        int* __restrict__ cur)
{
    int i = blockIdx.x*256 + threadIdx.x;
    if (i < NN){ int v = iptr[i] + bsum[i>>8]; iptr[i]=v; cur[i]=v; }
}

__global__ void k_scatter(const int* __restrict__ ei, int* __restrict__ cur,
                          int* __restrict__ esrc)
{
    int e = blockIdx.x*256 + threadIdx.x;
    if (e < NE){
        int d = ei[NE+e];
        if ((unsigned)d < NN){
            int p = atomicAdd(&cur[d], 1);
            if ((unsigned)p < NE) esrc[p] = ei[e];
        }
    }
}

// ---------------- GIN aggregation: wave-per-node, float2 lanes, 8-deep gather ----------------
__global__ __launch_bounds__(256) void k_agg(const float* __restrict__ x,
    const int* __restrict__ iptr, const int* __restrict__ esrc, float* __restrict__ h)
{
    int node = blockIdx.x*4 + (threadIdx.x >> 6);
    int lane = threadIdx.x & 63;
    int s = __builtin_amdgcn_readfirstlane(iptr[node]);
    int e = __builtin_amdgcn_readfirstlane(iptr[node+1]);
    const float2* __restrict__ xp = (const float2*)x;
    float2 acc = xp[(size_t)node*64 + lane];
    float2 accb = make_float2(0.f, 0.f);
    int j = s;
    for (; j+8 <= e; j += 8){
        int i0 = esrc[j+0], i1 = esrc[j+1], i2 = esrc[j+2], i3 = esrc[j+3];
        int i4 = esrc[j+4], i5 = esrc[j+5], i6 = esrc[j+6], i7 = esrc[j+7];
        float2 v0 = xp[(size_t)i0*64 + lane];
        float2 v1 = xp[(size_t)i1*64 + lane];
        float2 v2 = xp[(size_t)i2*64 + lane];
        float2 v3 = xp[(size_t)i3*64 + lane];
        float2 v4 = xp[(size_t)i4*64 + lane];
        float2 v5 = xp[(size_t)i5*64 + lane];
        float2 v6 = xp[(size_t)i6*64 + lane];
        float2 v7 = xp[(size_t)i7*64 + lane];
        acc.x  += (v0.x + v1.x) + (v2.x + v3.x);
        acc.y  += (v0.y + v1.y) + (v2.y + v3.y);
        accb.x += (v4.x + v5.x) + (v6.x + v7.x);
        accb.y += (v4.y + v5.y) + (v6.y + v7.y);
    }
    for (; j+4 <= e; j += 4){
        int i0 = esrc[j+0], i1 = esrc[j+1], i2 = esrc[j+2], i3 = esrc[j+3];
        float2 v0 = xp[(size_t)i0*64 + lane];
        float2 v1 = xp[(size_t)i1*64 + lane];
        float2 v2 = xp[(size_t)i2*64 + lane];
        float2 v3 = xp[(size_t)i3*64 + lane];
        acc.x += (v0.x + v1.x) + (v2.x + v3.x);
        acc.y += (v0.y + v1.y) + (v2.y + v3.y);
    }
    for (; j < e; j++){
        int i0 = esrc[j];
        float2 v = xp[(size_t)i0*64 + lane];
        acc.x += v.x; acc.y += v.y;
    }
    acc.x += accb.x; acc.y += accb.y;
    ((float2*)h)[(size_t)node*64 + lane] = acc;
}

// ---------------- per-graph sum pooling ----------------
__global__ __launch_bounds__(128) void k_pool(const float* __restrict__ x,
    const int* __restrict__ batch, float* __restrict__ aggr)
{
    int g = blockIdx.x, c = threadIdx.x;
    int lo=0, hi=NN;
    while (lo<hi){ int mid=(lo+hi)>>1; if (batch[mid] < g) lo=mid+1; else hi=mid; }
    int s0 = lo;
    hi = NN;
    while (lo<hi){ int mid=(lo+hi)>>1; if (batch[mid] < g+1) lo=mid+1; else hi=mid; }
    int e0 = lo;
    float a0=0.f, a1=0.f, a2=0.f, a3=0.f;
    int i = s0;
    for (; i+4 <= e0; i += 4){
        a0 += x[(size_t)(i+0)*H + c];
        a1 += x[(size_t)(i+1)*H + c];
        a2 += x[(size_t)(i+2)*H + c];
        a3 += x[(size_t)(i+3)*H + c];
    }
    for (; i < e0; i++) a0 += x[(size_t)i*H + c];
    aggr[g*H + c] = (a0+a1) + (a2+a3);
}

// ---------------- 4 heads + evidential outputs (FP32 OUTPUT) ----------------
__global__ __launch_bounds__(128) void k_heads(const float* __restrict__ aggr,
    const float* __restrict__ W1, const float* __restrict__ b1,
    const float* __restrict__ W2, const float* __restrict__ b2,
    float* __restrict__ out)
{
    __shared__ float a[H];
    __shared__ float red[H];
    __shared__ float outk[4];
    int g = blockIdx.x, c = threadIdx.x;
    a[c] = aggr[g*H + c];
    __syncthreads();
    for (int k=0;k<4;k++){
        const float* w = W1 + k*H*H;
        float acc = b1[k*H + c];
#pragma unroll 4
        for (int qq=0;qq<H;qq++) acc += a[qq]*w[qq*H + c];
        red[c] = fmaxf(acc, 0.f) * W2[k*H + c];
        __syncthreads();
        for (int sd=64; sd>0; sd>>=1){
            if (c < sd) red[c] += red[c+sd];
            __syncthreads();
        }
        if (c==0) outk[k] = red[0] + b2[k];
        __syncthreads();
    }
    if (c==0){
        float o0=outk[0], o1=outk[1], o2=outk[2], o3=outk[3];
        float alpha = fmaxf(softplusf(o0) + 1.f, 1.f + 1e-4f);
        float beta  = softplusf(o1);
        float nu    = softplusf(o2);
        float am1   = alpha - 1.f;
        float aleat = beta / am1;
        float epis  = beta / (am1 * nu);
        out[0*NG+g] = o3;
        out[1*NG+g] = aleat;
        out[2*NG+g] = epis;
        out[3*NG+g] = nu;
        out[4*NG+g] = alpha;
        out[5*NG+g] = beta;
    }
}

extern "C" void kernel_launch(void* const* d_in, const int* in_sizes, int n_in,
                              void* d_out, int out_size, void* d_ws, size_t ws_size,
                              hipStream_t stream)
{
    const int*   z     = (const int*)d_in[0];
    const float* pos   = (const float*)d_in[1];
    const int*   batch = (const int*)d_in[2];
    const int*   eidx  = (const int*)d_in[3];
    const float* emb   = (const float*)d_in[4];
    const float* Wp    = (const float*)d_in[5];
    const float* bp    = (const float*)d_in[6];
    const float* Wc    = (const float*)d_in[7];
    const float* bc    = (const float*)d_in[8];
    const float* gW1   = (const float*)d_in[9];
    const float* gb1   = (const float*)d_in[10];
    const float* gW2   = (const float*)d_in[11];
    const float* gb2   = (const float*)d_in[12];
    const float* hW1   = (const float*)d_in[13];
    const float* hb1   = (const float*)d_in[14];
    const float* hW2   = (const float*)d_in[15];
    const float* hb2   = (const float*)d_in[16];
    float* out = (float*)d_out;

    bool ok_sizes = (n_in == 17)
        && in_sizes[0] == NN && in_sizes[1] == NN*3 && in_sizes[2] == NN
        && in_sizes[3] == 2*NE && in_sizes[4] == 100*H
        && in_sizes[7] == 2*H*H && in_sizes[9] == 4*H*H
        && in_sizes[13] == 4*H*H && in_sizes[16] == 4;
    if (!ok_sizes){ k_sentinel<<<12, 256, 0, stream>>>(out, 600000.0f); return; }

    const size_t OFF_X    = 256;
    const size_t OFF_H    = 25600256;
    const size_t OFF_AGGR = 51200256;
    const size_t OFF_IPTR = 51462400;
    const size_t OFF_CUR  = 51662592;
    const size_t OFF_ESRC = 51862784;
    const size_t OFF_BSUM = 55062784;
    const size_t OFF_WF   = 55063808;   // 512 KB
    const size_t REQ      = 55588096;
    if (ws_size < REQ){ k_sentinel<<<12, 256, 0, stream>>>(out, 500000.0f); return; }

    char* ws = (char*)d_ws;
    float* x    = (float*)(ws + OFF_X);
    float* h    = (float*)(ws + OFF_H);
    float* aggr = (float*)(ws + OFF_AGGR);
    int*   iptr = (int*)(ws + OFF_IPTR);
    int*   cur  = (int*)(ws + OFF_CUR);
    int*   esrc = (int*)(ws + OFF_ESRC);
    int*   bsum = (int*)(ws + OFF_BSUM);
    uint4* wf   = (uint4*)(ws + OFF_WF);

    k_embed<<<(NN+63)/64, 256, 0, stream>>>(z, pos, emb, Wp, bp, Wc, bc, x, NN);

    k_wsplit<<<256, 64, 0, stream>>>(gW1, gW2, wf);

    k_zero<<<(NN+255)/256, 256, 0, stream>>>(cur, NN);
    k_count<<<(NE+255)/256, 256, 0, stream>>>(eidx, cur);
    k_scan1<<<196, 256, 0, stream>>>(cur, iptr, bsum);
    k_scan2<<<1, 64, 0, stream>>>(bsum, iptr, 196);
    k_scan3<<<196, 256, 0, stream>>>(iptr, bsum, cur);
    k_scatter<<<(NE+255)/256, 256, 0, stream>>>(eidx, cur, esrc);

    for (int l=0;l<4;l++){
        k_agg<<<NN/4, 256, 0, stream>>>(x, iptr, esrc, h);
        k_gin_mfma<<<(NN+63)/64, 256, 0, stream>>>(h,
            gb1 + (size_t)l*H, gb2 + (size_t)l*H, wf, x, l, (l<3)?1:0);
    }

    k_pool<<<NG, 128, 0, stream>>>(x, batch, aggr);
    k_heads<<<NG, 128, 0, stream>>>(aggr, hW1, hb1, hW2, hb2, out);
}

// Round 11
// 626.960 us; speedup vs baseline: 1.5835x; 1.5422x over previous
//
#include <hip/hip_runtime.h>
#include <stdint.h>

#define NN 50000
#define NE 800000
#define NG 512
#define H  128

typedef __attribute__((ext_vector_type(8))) short short8;
typedef __attribute__((ext_vector_type(16))) float f32x16;

union U4S8 { uint4 u; short8 s; };

__device__ __forceinline__ float softplusf(float x){
    return fmaxf(x, 0.f) + log1pf(expf(-fabsf(x)));
}

// round-to-nearest-even bf16 bits (high 16) of x
__device__ __forceinline__ unsigned rne_bf16_hi(float x){
    unsigned u = __float_as_uint(x);
    unsigned r = u + 0x7fffu + ((u >> 16) & 1u);
    return r & 0xffff0000u;
}

// split two fp32 into bf16-hi dword and bf16-lo dword (RNE split; residual ~2^-17)
__device__ __forceinline__ void split_pack(float x0, float x1, unsigned &hi, unsigned &lo){
    unsigned h0 = rne_bf16_hi(x0), h1 = rne_bf16_hi(x1);
    hi = (h0 >> 16) | h1;
    float l0 = x0 - __uint_as_float(h0);
    float l1 = x1 - __uint_as_float(h1);
    unsigned g0 = rne_bf16_hi(l0), g1 = rne_bf16_hi(l1);
    lo = (g0 >> 16) | g1;
}

// ---------------- sentinel writer ----------------
__global__ void k_sentinel(float* out, float val){
    int i = blockIdx.x*256 + threadIdx.x;
    if (i < 6*NG) out[i] = val;
}

// ---------------- W pre-split into MFMA B-fragment order ----------------
// wf layout: [mat(8)][hl(2)][ntg(4)][ks(8)][lane(64)] x 16B.  mat = layer*2 + phase.
// B-frag (32x32x16): lane holds B[k = ks*16 + (lane>>5)*8 + j][n = ntg*32 + (lane&31)], j=0..7.
__global__ __launch_bounds__(64) void k_wsplit(const float* __restrict__ gW1,
    const float* __restrict__ gW2, uint4* __restrict__ wf)
{
    int bid = blockIdx.x, lane = threadIdx.x;
    int mat = bid >> 5, ntg = (bid >> 3) & 3, ks = bid & 7;
    int l = mat >> 1;
    const float* W = (mat & 1) ? (gW2 + (size_t)l*H*H) : (gW1 + (size_t)l*H*H);
    int n  = ntg*32 + (lane & 31);
    int kb = ks*16 + (lane >> 5)*8;
    unsigned hi[4], lo[4];
#pragma unroll
    for (int d=0; d<4; d++){
        float x0 = W[(size_t)(kb + 2*d    )*H + n];
        float x1 = W[(size_t)(kb + 2*d + 1)*H + n];
        split_pack(x0, x1, hi[d], lo[d]);
    }
    int bh = ((mat*2 + 0)*4 + ntg)*8 + ks;
    int bl = ((mat*2 + 1)*4 + ntg)*8 + ks;
    wf[bh*64 + lane] = make_uint4(hi[0],hi[1],hi[2],hi[3]);
    wf[bl*64 + lane] = make_uint4(lo[0],lo[1],lo[2],lo[3]);
}

// ---------------- fused GIN MLP: LDS-staged bf16x2-split MFMA ----------------
// Block 256 thr = 4 waves; tile 64 rows x 128 cols; wave w: rt=w&1 (row half), cp=w>>1 (col half).
// A-fragments in LDS in FRAGMENT ORDER [rt(2)][ks(8)][lane(64)] x 16B (hi + lo arrays):
//   - ds_read_b128 per frag: lane-sequential -> conflict-free, 16B-aligned.
// B-fragments from wf (global, L2-hot, coalesced).
// Phase-1 output T split to bf16 and written BACK INTO LDS (no global round-trip).
__global__ __launch_bounds__(256) void k_gin_mfma(const float* __restrict__ hx,
    const float* __restrict__ b1, const float* __restrict__ b2,
    const uint4* __restrict__ wf, float* __restrict__ xout, int l, int relu2)
{
    __shared__ unsigned short AhiF[2*8*64*8];   // 16 KB
    __shared__ unsigned short AloF[2*8*64*8];   // 16 KB
    const int t = threadIdx.x, lane = t & 63, w = t >> 6;
    const int rt = w & 1, cp = w >> 1;
    const int mb = blockIdx.x * 64;
    const int c31 = lane & 31;
    const int q = lane >> 5;

    // ---- stage X tile (64x128 fp32, coalesced) -> split bf16 frag-order LDS ----
    {
        int r = t >> 2, c4 = t & 3;
        int gr = mb + r;
        const float* rowp = hx + (size_t)((gr < NN) ? gr : (NN-1))*H;
        int rt_s = r >> 5, r31 = r & 31;
        int q_s = c4 >> 1, j4 = (c4 & 1)*4;
#pragma unroll
        for (int i=0;i<8;i++){
            int col = c4*4 + i*16;
            float4 v = *(const float4*)(rowp + col);
            unsigned h0,l0,h1,l1;
            split_pack(v.x, v.y, h0, l0);
            split_pack(v.z, v.w, h1, l1);
            int idx = ((rt_s*8 + i)*64 + q_s*32 + r31)*8 + j4;
            *(uint2*)&AhiF[idx] = make_uint2(h0, h1);
            *(uint2*)&AloF[idx] = make_uint2(l0, l1);
        }
    }
    __syncthreads();

    const float bv1a = b1[64*cp + c31], bv1b = b1[64*cp + 32 + c31];
    const float bv2a = b2[64*cp + c31], bv2b = b2[64*cp + 32 + c31];
    const int mat1 = l*2, mat2 = l*2 + 1;

    f32x16 acc0, acc1;
#pragma unroll
    for (int i=0;i<16;i++){ acc0[i]=0.f; acc1[i]=0.f; }

    // ---- phase 1: T = relu(X@W1 + b1) ----
#pragma unroll
    for (int ks=0; ks<8; ks++){
        U4S8 ah, al, bh0, bl0, bh1, bl1;
        ah.u  = *(const uint4*)&AhiF[((rt*8+ks)*64 + lane)*8];
        al.u  = *(const uint4*)&AloF[((rt*8+ks)*64 + lane)*8];
        bh0.u = wf[(((mat1*2+0)*4 + 2*cp+0)*8 + ks)*64 + lane];
        bl0.u = wf[(((mat1*2+1)*4 + 2*cp+0)*8 + ks)*64 + lane];
        bh1.u = wf[(((mat1*2+0)*4 + 2*cp+1)*8 + ks)*64 + lane];
        bl1.u = wf[(((mat1*2+1)*4 + 2*cp+1)*8 + ks)*64 + lane];
        acc0 = __builtin_amdgcn_mfma_f32_32x32x16_bf16(ah.s, bh0.s, acc0, 0,0,0);
        acc0 = __builtin_amdgcn_mfma_f32_32x32x16_bf16(ah.s, bl0.s, acc0, 0,0,0);
        acc0 = __builtin_amdgcn_mfma_f32_32x32x16_bf16(al.s, bh0.s, acc0, 0,0,0);
        acc1 = __builtin_amdgcn_mfma_f32_32x32x16_bf16(ah.s, bh1.s, acc1, 0,0,0);
        acc1 = __builtin_amdgcn_mfma_f32_32x32x16_bf16(ah.s, bl1.s, acc1, 0,0,0);
        acc1 = __builtin_amdgcn_mfma_f32_32x32x16_bf16(al.s, bh1.s, acc1, 0,0,0);
    }

    // ---- T -> LDS frag-order (bf16 hi/lo), barrier-protected ----
    __syncthreads();   // all waves done reading X fragments
#pragma unroll
    for (int reg=0; reg<16; reg++){
        int r31o = (reg & 3) + 8*(reg >> 2) + 4*q;   // row within 32-row tile
        float v0 = fmaxf(acc0[reg] + bv1a, 0.f);
        float v1 = fmaxf(acc1[reg] + bv1b, 0.f);
        {
            int k = 64*cp + c31;
            int idx = ((rt*8 + (k>>4))*64 + ((k>>3)&1)*32 + r31o)*8 + (k & 7);
            unsigned hb = rne_bf16_hi(v0);
            AhiF[idx] = (unsigned short)(hb >> 16);
            AloF[idx] = (unsigned short)(rne_bf16_hi(v0 - __uint_as_float(hb)) >> 16);
        }
        {
            int k = 64*cp + 32 + c31;
            int idx = ((rt*8 + (k>>4))*64 + ((k>>3)&1)*32 + r31o)*8 + (k & 7);
            unsigned hb = rne_bf16_hi(v1);
            AhiF[idx] = (unsigned short)(hb >> 16);
            AloF[idx] = (unsigned short)(rne_bf16_hi(v1 - __uint_as_float(hb)) >> 16);
        }
    }
    __syncthreads();

    // ---- phase 2: Y = T@W2 + b2 ----
#pragma unroll
    for (int i=0;i<16;i++){ acc0[i]=0.f; acc1[i]=0.f; }
#pragma unroll
    for (int ks=0; ks<8; ks++){
        U4S8 ah, al, bh0, bl0, bh1, bl1;
        ah.u  = *(const uint4*)&AhiF[((rt*8+ks)*64 + lane)*8];
        al.u  = *(const uint4*)&AloF[((rt*8+ks)*64 + lane)*8];
        bh0.u = wf[(((mat2*2+0)*4 + 2*cp+0)*8 + ks)*64 + lane];
        bl0.u = wf[(((mat2*2+1)*4 + 2*cp+0)*8 + ks)*64 + lane];
        bh1.u = wf[(((mat2*2+0)*4 + 2*cp+1)*8 + ks)*64 + lane];
        bl1.u = wf[(((mat2*2+1)*4 + 2*cp+1)*8 + ks)*64 + lane];
        acc0 = __builtin_amdgcn_mfma_f32_32x32x16_bf16(ah.s, bh0.s, acc0, 0,0,0);
        acc0 = __builtin_amdgcn_mfma_f32_32x32x16_bf16(ah.s, bl0.s, acc0, 0,0,0);
        acc0 = __builtin_amdgcn_mfma_f32_32x32x16_bf16(al.s, bh0.s, acc0, 0,0,0);
        acc1 = __builtin_amdgcn_mfma_f32_32x32x16_bf16(ah.s, bh1.s, acc1, 0,0,0);
        acc1 = __builtin_amdgcn_mfma_f32_32x32x16_bf16(ah.s, bl1.s, acc1, 0,0,0);
        acc1 = __builtin_amdgcn_mfma_f32_32x32x16_bf16(al.s, bh1.s, acc1, 0,0,0);
    }

    // ---- epilogue: fp32 to global ----
#pragma unroll
    for (int reg=0; reg<16; reg++){
        int row = 32*rt + (reg & 3) + 8*(reg >> 2) + 4*q;
        int mm = mb + row;
        if (mm < NN){
            float v0 = acc0[reg] + bv2a;
            float v1 = acc1[reg] + bv2b;
            if (relu2){ v0 = fmaxf(v0, 0.f); v1 = fmaxf(v1, 0.f); }
            xout[(size_t)mm*H + 64*cp      + c31] = v0;
            xout[(size_t)mm*H + 64*cp + 32 + c31] = v1;
        }
    }
}

// ---------------- fused initial embedding GEMM (unchanged) ----------------
__global__ __launch_bounds__(256) void k_embed(const int* __restrict__ z,
    const float* __restrict__ pos, const float* __restrict__ emb,
    const float* __restrict__ Wp, const float* __restrict__ bp,
    const float* __restrict__ Wc, const float* __restrict__ bc,
    float* __restrict__ Y, int M)
{
    __shared__ float Xs[64*66];
    __shared__ float Ws[64*128];
    const int t  = threadIdx.x;
    const int tn = t & 15, tm = t >> 4;
    const int ca = tn*4, cb = 64 + tn*4;
    const int m0 = tm*4;
    const int mb = blockIdx.x*64;
    float acc[4][8];
#pragma unroll
    for (int i=0;i<4;i++)
#pragma unroll
      for (int j=0;j<8;j++) acc[i][j]=0.f;

    for (int k0=0; k0<256; k0+=64){
        {
            const int kq = t & 15, mr = t >> 4;
#pragma unroll
            for (int p=0;p<4;p++){
                int mm = mr + p*16;
                int gr = mb + mm;
                float4 v = make_float4(0.f,0.f,0.f,0.f);
                if (gr < M){
                    if (k0 < 128){
                        v = *(const float4*)(emb + (size_t)z[gr]*H + k0 + kq*4);
                    } else {
                        int c = (k0 - 128) + kq*4;
                        float4 w0 = *(const float4*)(Wp + c);
                        float4 w1 = *(const float4*)(Wp + H + c);
                        float4 w2 = *(const float4*)(Wp + 2*H + c);
                        float4 bb = *(const float4*)(bp + c);
                        float p0 = pos[gr*3+0], p1 = pos[gr*3+1], p2 = pos[gr*3+2];
                        v.x = p0*w0.x + p1*w1.x + p2*w2.x + bb.x;
                        v.y = p0*w0.y + p1*w1.y + p2*w2.y + bb.y;
                        v.z = p0*w0.z + p1*w1.z + p2*w2.z + bb.z;
                        v.w = p0*w0.w + p1*w1.w + p2*w2.w + bb.w;
                    }
                }
                float* d = &Xs[mm*66 + kq*4];
                d[0]=v.x; d[1]=v.y; d[2]=v.z; d[3]=v.w;
            }
        }
        {
            const int kk = t >> 2, c0 = (t & 3)*32;
            const float4* wr = (const float4*)(Wc + (size_t)(k0+kk)*H + c0);
            float4* d = (float4*)&Ws[kk*H + c0];
#pragma unroll
            for (int qq=0;qq<8;qq++) d[qq] = wr[qq];
        }
        __syncthreads();
#pragma unroll 8
        for (int kk=0; kk<64; kk++){
            float x0=Xs[(m0+0)*66+kk], x1=Xs[(m0+1)*66+kk];
            float x2=Xs[(m0+2)*66+kk], x3=Xs[(m0+3)*66+kk];
            float4 wa = *(const float4*)&Ws[kk*H + ca];
            float4 wb = *(const float4*)&Ws[kk*H + cb];
            float wv[8] = {wa.x,wa.y,wa.z,wa.w, wb.x,wb.y,wb.z,wb.w};
#pragma unroll
            for (int j=0;j<8;j++){
                acc[0][j] += x0*wv[j];
                acc[1][j] += x1*wv[j];
                acc[2][j] += x2*wv[j];
                acc[3][j] += x3*wv[j];
            }
        }
        __syncthreads();
    }
    float4 bvA = *(const float4*)(bc + ca);
    float4 bvB = *(const float4*)(bc + cb);
    float bv[8] = {bvA.x,bvA.y,bvA.z,bvA.w, bvB.x,bvB.y,bvB.z,bvB.w};
#pragma unroll
    for (int i=0;i<4;i++){
        int gr = mb + m0 + i;
        if (gr < M){
            float o[8];
#pragma unroll
            for (int j=0;j<8;j++) o[j] = fmaxf(acc[i][j] + bv[j], 0.f);
            *(float4*)(Y + (size_t)gr*H + ca) = make_float4(o[0],o[1],o[2],o[3]);
            *(float4*)(Y + (size_t)gr*H + cb) = make_float4(o[4],o[5],o[6],o[7]);
        }
    }
}

// ---------------- CSR build (by dst) ----------------
__global__ void k_zero(int* p, int n){ int i=blockIdx.x*256+threadIdx.x; if(i<n) p[i]=0; }

__global__ void k_count(const int* __restrict__ ei, int* __restrict__ cnt){
    int e = blockIdx.x*256+threadIdx.x;
    if (e < NE){ int d = ei[NE+e]; if ((unsigned)d < NN) atomicAdd(&cnt[d], 1); }
}

__global__ __launch_bounds__(256) void k_scan1(const int* __restrict__ cnt,
    int* __restrict__ iptr, int* __restrict__ bsum)
{
    __shared__ int s[256];
    int t = threadIdx.x, i = blockIdx.x*256 + t;
    int v = (i < NN) ? cnt[i] : 0;
    s[t] = v;
    for (int off=1; off<256; off<<=1){
        __syncthreads();
        int tv = (t >= off) ? s[t-off] : 0;
        __syncthreads();
        s[t] += tv;
    }
    __syncthreads();
    if (i < NN) iptr[i] = s[t] - v;
    if (t == 255) bsum[blockIdx.x] = s[255];
}

__global__ void k_scan2(int* bsum, int* iptr, int nb){
    if (threadIdx.x==0 && blockIdx.x==0){
        int run = 0;
        for (int b=0;b<nb;b++){ int v=bsum[b]; bsum[b]=run; run+=v; }
        iptr[NN] = run;
    }
}

__global__ void k_scan3(int* __restrict__ iptr, const int* __restrict__ bsum,
                        int* __restrict__ cur)
{
    int i = blockIdx.x*256 + threadIdx.x;
    if (i < NN){ int v = iptr[i] + bsum[i>>8]; iptr[i]=v; cur[i]=v; }
}

__global__ void k_scatter(const int* __restrict__ ei, int* __restrict__ cur,
                          int* __restrict__ esrc)
{
    int e = blockIdx.x*256 + threadIdx.x;
    if (e < NE){
        int d = ei[NE+e];
        if ((unsigned)d < NN){
            int p = atomicAdd(&cur[d], 1);
            if ((unsigned)p < NE) esrc[p] = ei[e];
        }
    }
}

// ---------------- GIN aggregation: wave-per-node, float2 lanes, 8-deep gather ----------------
__global__ __launch_bounds__(256) void k_agg(const float* __restrict__ x,
    const int* __restrict__ iptr, const int* __restrict__ esrc, float* __restrict__ h)
{
    int node = blockIdx.x*4 + (threadIdx.x >> 6);
    int lane = threadIdx.x & 63;
    int s = __builtin_amdgcn_readfirstlane(iptr[node]);
    int e = __builtin_amdgcn_readfirstlane(iptr[node+1]);
    const float2* __restrict__ xp = (const float2*)x;
    float2 acc = xp[(size_t)node*64 + lane];
    float2 accb = make_float2(0.f, 0.f);
    int j = s;
    for (; j+8 <= e; j += 8){
        int i0 = esrc[j+0], i1 = esrc[j+1], i2 = esrc[j+2], i3 = esrc[j+3];
        int i4 = esrc[j+4], i5 = esrc[j+5], i6 = esrc[j+6], i7 = esrc[j+7];
        float2 v0 = xp[(size_t)i0*64 + lane];
        float2 v1 = xp[(size_t)i1*64 + lane];
        float2 v2 = xp[(size_t)i2*64 + lane];
        float2 v3 = xp[(size_t)i3*64 + lane];
        float2 v4 = xp[(size_t)i4*64 + lane];
        float2 v5 = xp[(size_t)i5*64 + lane];
        float2 v6 = xp[(size_t)i6*64 + lane];
        float2 v7 = xp[(size_t)i7*64 + lane];
        acc.x  += (v0.x + v1.x) + (v2.x + v3.x);
        acc.y  += (v0.y + v1.y) + (v2.y + v3.y);
        accb.x += (v4.x + v5.x) + (v6.x + v7.x);
        accb.y += (v4.y + v5.y) + (v6.y + v7.y);
    }
    for (; j+4 <= e; j += 4){
        int i0 = esrc[j+0], i1 = esrc[j+1], i2 = esrc[j+2], i3 = esrc[j+3];
        float2 v0 = xp[(size_t)i0*64 + lane];
        float2 v1 = xp[(size_t)i1*64 + lane];
        float2 v2 = xp[(size_t)i2*64 + lane];
        float2 v3 = xp[(size_t)i3*64 + lane];
        acc.x += (v0.x + v1.x) + (v2.x + v3.x);
        acc.y += (v0.y + v1.y) + (v2.y + v3.y);
    }
    for (; j < e; j++){
        int i0 = esrc[j];
        float2 v = xp[(size_t)i0*64 + lane];
        acc.x += v.x; acc.y += v.y;
    }
    acc.x += accb.x; acc.y += accb.y;
    ((float2*)h)[(size_t)node*64 + lane] = acc;
}

// ---------------- per-graph sum pooling ----------------
__global__ __launch_bounds__(128) void k_pool(const float* __restrict__ x,
    const int* __restrict__ batch, float* __restrict__ aggr)
{
    int g = blockIdx.x, c = threadIdx.x;
    int lo=0, hi=NN;
    while (lo<hi){ int mid=(lo+hi)>>1; if (batch[mid] < g) lo=mid+1; else hi=mid; }
    int s0 = lo;
    hi = NN;
    while (lo<hi){ int mid=(lo+hi)>>1; if (batch[mid] < g+1) lo=mid+1; else hi=mid; }
    int e0 = lo;
    float a0=0.f, a1=0.f, a2=0.f, a3=0.f;
    int i = s0;
    for (; i+4 <= e0; i += 4){
        a0 += x[(size_t)(i+0)*H + c];
        a1 += x[(size_t)(i+1)*H + c];
        a2 += x[(size_t)(i+2)*H + c];
        a3 += x[(size_t)(i+3)*H + c];
    }
    for (; i < e0; i++) a0 += x[(size_t)i*H + c];
    aggr[g*H + c] = (a0+a1) + (a2+a3);
}

// ---------------- 4 heads + evidential outputs (FP32 OUTPUT) ----------------
__global__ __launch_bounds__(128) void k_heads(const float* __restrict__ aggr,
    const float* __restrict__ W1, const float* __restrict__ b1,
    const float* __restrict__ W2, const float* __restrict__ b2,
    float* __restrict__ out)
{
    __shared__ float a[H];
    __shared__ float red[H];
    __shared__ float outk[4];
    int g = blockIdx.x, c = threadIdx.x;
    a[c] = aggr[g*H + c];
    __syncthreads();
    for (int k=0;k<4;k++){
        const float* w = W1 + k*H*H;
        float acc = b1[k*H + c];
#pragma unroll 4
        for (int qq=0;qq<H;qq++) acc += a[qq]*w[qq*H + c];
        red[c] = fmaxf(acc, 0.f) * W2[k*H + c];
        __syncthreads();
        for (int sd=64; sd>0; sd>>=1){
            if (c < sd) red[c] += red[c+sd];
            __syncthreads();
        }
        if (c==0) outk[k] = red[0] + b2[k];
        __syncthreads();
    }
    if (c==0){
        float o0=outk[0], o1=outk[1], o2=outk[2], o3=outk[3];
        float alpha = fmaxf(softplusf(o0) + 1.f, 1.f + 1e-4f);
        float beta  = softplusf(o1);
        float nu    = softplusf(o2);
        float am1   = alpha - 1.f;
        float aleat = beta / am1;
        float epis  = beta / (am1 * nu);
        out[0*NG+g] = o3;
        out[1*NG+g] = aleat;
        out[2*NG+g] = epis;
        out[3*NG+g] = nu;
        out[4*NG+g] = alpha;
        out[5*NG+g] = beta;
    }
}

extern "C" void kernel_launch(void* const* d_in, const int* in_sizes, int n_in,
                              void* d_out, int out_size, void* d_ws, size_t ws_size,
                              hipStream_t stream)
{
    const int*   z     = (const int*)d_in[0];
    const float* pos   = (const float*)d_in[1];
    const int*   batch = (const int*)d_in[2];
    const int*   eidx  = (const int*)d_in[3];
    const float* emb   = (const float*)d_in[4];
    const float* Wp    = (const float*)d_in[5];
    const float* bp    = (const float*)d_in[6];
    const float* Wc    = (const float*)d_in[7];
    const float* bc    = (const float*)d_in[8];
    const float* gW1   = (const float*)d_in[9];
    const float* gb1   = (const float*)d_in[10];
    const float* gW2   = (const float*)d_in[11];
    const float* gb2   = (const float*)d_in[12];
    const float* hW1   = (const float*)d_in[13];
    const float* hb1   = (const float*)d_in[14];
    const float* hW2   = (const float*)d_in[15];
    const float* hb2   = (const float*)d_in[16];
    float* out = (float*)d_out;

    bool ok_sizes = (n_in == 17)
        && in_sizes[0] == NN && in_sizes[1] == NN*3 && in_sizes[2] == NN
        && in_sizes[3] == 2*NE && in_sizes[4] == 100*H
        && in_sizes[7] == 2*H*H && in_sizes[9] == 4*H*H
        && in_sizes[13] == 4*H*H && in_sizes[16] == 4;
    if (!ok_sizes){ k_sentinel<<<12, 256, 0, stream>>>(out, 600000.0f); return; }

    const size_t OFF_X    = 256;
    const size_t OFF_H    = 25600256;
    const size_t OFF_AGGR = 51200256;
    const size_t OFF_IPTR = 51462400;
    const size_t OFF_CUR  = 51662592;
    const size_t OFF_ESRC = 51862784;
    const size_t OFF_BSUM = 55062784;
    const size_t OFF_WF   = 55063808;   // 512 KB
    const size_t REQ      = 55588096;
    if (ws_size < REQ){ k_sentinel<<<12, 256, 0, stream>>>(out, 500000.0f); return; }

    char* ws = (char*)d_ws;
    float* x    = (float*)(ws + OFF_X);
    float* h    = (float*)(ws + OFF_H);
    float* aggr = (float*)(ws + OFF_AGGR);
    int*   iptr = (int*)(ws + OFF_IPTR);
    int*   cur  = (int*)(ws + OFF_CUR);
    int*   esrc = (int*)(ws + OFF_ESRC);
    int*   bsum = (int*)(ws + OFF_BSUM);
    uint4* wf   = (uint4*)(ws + OFF_WF);

    k_embed<<<(NN+63)/64, 256, 0, stream>>>(z, pos, emb, Wp, bp, Wc, bc, x, NN);

    k_wsplit<<<256, 64, 0, stream>>>(gW1, gW2, wf);

    k_zero<<<(NN+255)/256, 256, 0, stream>>>(cur, NN);
    k_count<<<(NE+255)/256, 256, 0, stream>>>(eidx, cur);
    k_scan1<<<196, 256, 0, stream>>>(cur, iptr, bsum);
    k_scan2<<<1, 64, 0, stream>>>(bsum, iptr, 196);
    k_scan3<<<196, 256, 0, stream>>>(iptr, bsum, cur);
    k_scatter<<<(NE+255)/256, 256, 0, stream>>>(eidx, cur, esrc);

    for (int l=0;l<4;l++){
        k_agg<<<NN/4, 256, 0, stream>>>(x, iptr, esrc, h);
        k_gin_mfma<<<(NN+63)/64, 256, 0, stream>>>(h,
            gb1 + (size_t)l*H, gb2 + (size_t)l*H, wf, x, l, (l<3)?1:0);
    }

    k_pool<<<NG, 128, 0, stream>>>(x, batch, aggr);
    k_heads<<<NG, 128, 0, stream>>>(aggr, hW1, hb1, hW2, hb2, out);
}

// Round 12
// 509.435 us; speedup vs baseline: 1.9489x; 1.2307x over previous
//
#include <hip/hip_runtime.h>
#include <stdint.h>

#define NN 50000
#define NE 800000
#define NG 512
#define H  128

typedef __attribute__((ext_vector_type(8))) short short8;
typedef __attribute__((ext_vector_type(16))) float f32x16;

union U4S8 { uint4 u; short8 s; };

__device__ __forceinline__ float softplusf(float x){
    return fmaxf(x, 0.f) + log1pf(expf(-fabsf(x)));
}

// round-to-nearest-even bf16 bits (high 16) of x
__device__ __forceinline__ unsigned rne_bf16_hi(float x){
    unsigned u = __float_as_uint(x);
    unsigned r = u + 0x7fffu + ((u >> 16) & 1u);
    return r & 0xffff0000u;
}

// split two fp32 into bf16-hi dword and bf16-lo dword (RNE split; residual ~2^-17)
__device__ __forceinline__ void split_pack(float x0, float x1, unsigned &hi, unsigned &lo){
    unsigned h0 = rne_bf16_hi(x0), h1 = rne_bf16_hi(x1);
    hi = (h0 >> 16) | h1;
    float l0 = x0 - __uint_as_float(h0);
    float l1 = x1 - __uint_as_float(h1);
    unsigned g0 = rne_bf16_hi(l0), g1 = rne_bf16_hi(l1);
    lo = (g0 >> 16) | g1;
}

// pack adjacent-lane pair (v at col c, partner at col c+1) into one bf16x2 dword; even lanes store
__device__ __forceinline__ void store_xb_pair(unsigned* __restrict__ xbu, int mm,
                                              int cp, int c31, int lane, float v0, float v1){
    float p0 = __shfl_xor(v0, 1);
    float p1 = __shfl_xor(v1, 1);
    if (!(lane & 1)){
        unsigned u0 = (rne_bf16_hi(v0) >> 16) | (rne_bf16_hi(p0) & 0xffff0000u);
        unsigned u1 = (rne_bf16_hi(v1) >> 16) | (rne_bf16_hi(p1) & 0xffff0000u);
        xbu[(size_t)mm*64 + 32*cp      + (c31>>1)] = u0;
        xbu[(size_t)mm*64 + 32*cp + 16 + (c31>>1)] = u1;
    }
}

// ---------------- sentinel writer ----------------
__global__ void k_sentinel(float* out, float val){
    int i = blockIdx.x*256 + threadIdx.x;
    if (i < 6*NG) out[i] = val;
}

// ---------------- GIN W pre-split into MFMA B-fragment order ----------------
// wf layout: [mat(8)][hl(2)][ntg(4)][ks(8)][lane(64)] x 16B.  mat = layer*2 + phase.
__global__ __launch_bounds__(64) void k_wsplit(const float* __restrict__ gW1,
    const float* __restrict__ gW2, uint4* __restrict__ wf)
{
    int bid = blockIdx.x, lane = threadIdx.x;
    int mat = bid >> 5, ntg = (bid >> 3) & 3, ks = bid & 7;
    int l = mat >> 1;
    const float* W = (mat & 1) ? (gW2 + (size_t)l*H*H) : (gW1 + (size_t)l*H*H);
    int n  = ntg*32 + (lane & 31);
    int kb = ks*16 + (lane >> 5)*8;
    unsigned hi[4], lo[4];
#pragma unroll
    for (int d=0; d<4; d++){
        float x0 = W[(size_t)(kb + 2*d    )*H + n];
        float x1 = W[(size_t)(kb + 2*d + 1)*H + n];
        split_pack(x0, x1, hi[d], lo[d]);
    }
    int bh = ((mat*2 + 0)*4 + ntg)*8 + ks;
    int bl = ((mat*2 + 1)*4 + ntg)*8 + ks;
    wf[bh*64 + lane] = make_uint4(hi[0],hi[1],hi[2],hi[3]);
    wf[bl*64 + lane] = make_uint4(lo[0],lo[1],lo[2],lo[3]);
}

// ---------------- W_comb (256x128) pre-split: wcf [hl(2)][ntg(4)][ks(16)][lane(64)] x 16B ----
__global__ __launch_bounds__(64) void k_wsplit_embed(const float* __restrict__ Wc,
    uint4* __restrict__ wcf)
{
    int bid = blockIdx.x, lane = threadIdx.x;
    int ntg = bid >> 4, ks = bid & 15;
    int n  = ntg*32 + (lane & 31);
    int kb = ks*16 + (lane >> 5)*8;
    unsigned hi[4], lo[4];
#pragma unroll
    for (int d=0; d<4; d++){
        float x0 = Wc[(size_t)(kb + 2*d    )*H + n];
        float x1 = Wc[(size_t)(kb + 2*d + 1)*H + n];
        split_pack(x0, x1, hi[d], lo[d]);
    }
    wcf[((0*4 + ntg)*16 + ks)*64 + lane] = make_uint4(hi[0],hi[1],hi[2],hi[3]);
    wcf[((1*4 + ntg)*16 + ks)*64 + lane] = make_uint4(lo[0],lo[1],lo[2],lo[3]);
}

// ---------------- initial embedding via MFMA ----------------
// x = relu( concat(embed_tab[z], pos@W_pos+b_pos) @ W_comb + b_comb ); also emits xb (bf16 copy).
// K=256 in two K=128 chunks; A staged into frag-order LDS (32 KB); B from wcf.
__global__ __launch_bounds__(256) void k_embed_mfma(const int* __restrict__ z,
    const float* __restrict__ pos, const float* __restrict__ emb,
    const float* __restrict__ Wp, const float* __restrict__ bp,
    const float* __restrict__ bc, const uint4* __restrict__ wcf,
    float* __restrict__ xout, unsigned* __restrict__ xbu)
{
    __shared__ unsigned short AhiF[2*8*64*8];   // 16 KB (current K-half)
    __shared__ unsigned short AloF[2*8*64*8];   // 16 KB
    const int t = threadIdx.x, lane = t & 63, w = t >> 6;
    const int rt = w & 1, cp = w >> 1;
    const int mb = blockIdx.x * 64;
    const int c31 = lane & 31;
    const int q = lane >> 5;

    // staging ids
    const int r = t >> 2, c4 = t & 3;
    const int gr = mb + r;
    const int gre = (gr < NN) ? gr : (NN-1);
    const int zr = z[gre];
    const float p0 = pos[gre*3+0], p1 = pos[gre*3+1], p2 = pos[gre*3+2];
    const int rt_s = r >> 5, r31s = r & 31;

    f32x16 acc0, acc1;
#pragma unroll
    for (int i=0;i<16;i++){ acc0[i]=0.f; acc1[i]=0.f; }

#pragma unroll
    for (int kh2=0; kh2<2; kh2++){
        if (kh2) __syncthreads();   // protect restage against previous reads
        // ---- stage this K-half (128 cols) ----
#pragma unroll
        for (int i=0;i<8;i++){
            int cl = c4*4 + i*16;           // 0..124, col within half
            float4 v;
            if (kh2 == 0){
                v = *(const float4*)(emb + (size_t)zr*H + cl);
            } else {
                float4 w0 = *(const float4*)(Wp + cl);
                float4 w1 = *(const float4*)(Wp + H + cl);
                float4 w2 = *(const float4*)(Wp + 2*H + cl);
                float4 bb = *(const float4*)(bp + cl);
                v.x = p0*w0.x + p1*w1.x + p2*w2.x + bb.x;
                v.y = p0*w0.y + p1*w1.y + p2*w2.y + bb.y;
                v.z = p0*w0.z + p1*w1.z + p2*w2.z + bb.z;
                v.w = p0*w0.w + p1*w1.w + p2*w2.w + bb.w;
            }
            unsigned h0,l0,h1,l1;
            split_pack(v.x, v.y, h0, l0);
            split_pack(v.z, v.w, h1, l1);
            int idx = ((rt_s*8 + (cl>>4))*64 + ((cl>>3)&1)*32 + r31s)*8 + (cl & 7);
            *(uint2*)&AhiF[idx] = make_uint2(h0, h1);
            *(uint2*)&AloF[idx] = make_uint2(l0, l1);
        }
        __syncthreads();
        // ---- MFMA over this K-half ----
#pragma unroll
        for (int ks=0; ks<8; ks++){
            int ksg = kh2*8 + ks;
            U4S8 ah, al, bh0, bl0, bh1, bl1;
            ah.u  = *(const uint4*)&AhiF[((rt*8+ks)*64 + lane)*8];
            al.u  = *(const uint4*)&AloF[((rt*8+ks)*64 + lane)*8];
            bh0.u = wcf[((0*4 + 2*cp+0)*16 + ksg)*64 + lane];
            bl0.u = wcf[((1*4 + 2*cp+0)*16 + ksg)*64 + lane];
            bh1.u = wcf[((0*4 + 2*cp+1)*16 + ksg)*64 + lane];
            bl1.u = wcf[((1*4 + 2*cp+1)*16 + ksg)*64 + lane];
            acc0 = __builtin_amdgcn_mfma_f32_32x32x16_bf16(ah.s, bh0.s, acc0, 0,0,0);
            acc0 = __builtin_amdgcn_mfma_f32_32x32x16_bf16(ah.s, bl0.s, acc0, 0,0,0);
            acc0 = __builtin_amdgcn_mfma_f32_32x32x16_bf16(al.s, bh0.s, acc0, 0,0,0);
            acc1 = __builtin_amdgcn_mfma_f32_32x32x16_bf16(ah.s, bh1.s, acc1, 0,0,0);
            acc1 = __builtin_amdgcn_mfma_f32_32x32x16_bf16(ah.s, bl1.s, acc1, 0,0,0);
            acc1 = __builtin_amdgcn_mfma_f32_32x32x16_bf16(al.s, bh1.s, acc1, 0,0,0);
        }
    }

    const float bva = bc[64*cp + c31], bvb = bc[64*cp + 32 + c31];
#pragma unroll
    for (int reg=0; reg<16; reg++){
        int row = 32*rt + (reg & 3) + 8*(reg >> 2) + 4*q;
        int mm = mb + row;
        if (mm < NN){
            float v0 = fmaxf(acc0[reg] + bva, 0.f);
            float v1 = fmaxf(acc1[reg] + bvb, 0.f);
            xout[(size_t)mm*H + 64*cp      + c31] = v0;
            xout[(size_t)mm*H + 64*cp + 32 + c31] = v1;
            store_xb_pair(xbu, mm, cp, c31, lane, v0, v1);
        }
    }
}

// ---------------- fused GIN MLP: LDS-staged bf16x2-split MFMA (round-11 + xb emit) ----------------
__global__ __launch_bounds__(256) void k_gin_mfma(const float* __restrict__ hx,
    const float* __restrict__ b1, const float* __restrict__ b2,
    const uint4* __restrict__ wf, float* __restrict__ xout,
    unsigned* __restrict__ xbu, int l, int relu2)
{
    __shared__ unsigned short AhiF[2*8*64*8];   // 16 KB
    __shared__ unsigned short AloF[2*8*64*8];   // 16 KB
    const int t = threadIdx.x, lane = t & 63, w = t >> 6;
    const int rt = w & 1, cp = w >> 1;
    const int mb = blockIdx.x * 64;
    const int c31 = lane & 31;
    const int q = lane >> 5;

    // ---- stage X tile (64x128 fp32, coalesced) -> split bf16 frag-order LDS ----
    {
        int r = t >> 2, c4 = t & 3;
        int gr = mb + r;
        const float* rowp = hx + (size_t)((gr < NN) ? gr : (NN-1))*H;
        int rt_s = r >> 5, r31 = r & 31;
#pragma unroll
        for (int i=0;i<8;i++){
            int col = c4*4 + i*16;
            float4 v = *(const float4*)(rowp + col);
            unsigned h0,l0,h1,l1;
            split_pack(v.x, v.y, h0, l0);
            split_pack(v.z, v.w, h1, l1);
            int idx = ((rt_s*8 + i)*64 + ((col>>3)&1)*32 + r31)*8 + (col & 7);
            *(uint2*)&AhiF[idx] = make_uint2(h0, h1);
            *(uint2*)&AloF[idx] = make_uint2(l0, l1);
        }
    }
    __syncthreads();

    const float bv1a = b1[64*cp + c31], bv1b = b1[64*cp + 32 + c31];
    const float bv2a = b2[64*cp + c31], bv2b = b2[64*cp + 32 + c31];
    const int mat1 = l*2, mat2 = l*2 + 1;

    f32x16 acc0, acc1;
#pragma unroll
    for (int i=0;i<16;i++){ acc0[i]=0.f; acc1[i]=0.f; }

    // ---- phase 1: T = relu(X@W1 + b1) ----
#pragma unroll
    for (int ks=0; ks<8; ks++){
        U4S8 ah, al, bh0, bl0, bh1, bl1;
        ah.u  = *(const uint4*)&AhiF[((rt*8+ks)*64 + lane)*8];
        al.u  = *(const uint4*)&AloF[((rt*8+ks)*64 + lane)*8];
        bh0.u = wf[(((mat1*2+0)*4 + 2*cp+0)*8 + ks)*64 + lane];
        bl0.u = wf[(((mat1*2+1)*4 + 2*cp+0)*8 + ks)*64 + lane];
        bh1.u = wf[(((mat1*2+0)*4 + 2*cp+1)*8 + ks)*64 + lane];
        bl1.u = wf[(((mat1*2+1)*4 + 2*cp+1)*8 + ks)*64 + lane];
        acc0 = __builtin_amdgcn_mfma_f32_32x32x16_bf16(ah.s, bh0.s, acc0, 0,0,0);
        acc0 = __builtin_amdgcn_mfma_f32_32x32x16_bf16(ah.s, bl0.s, acc0, 0,0,0);
        acc0 = __builtin_amdgcn_mfma_f32_32x32x16_bf16(al.s, bh0.s, acc0, 0,0,0);
        acc1 = __builtin_amdgcn_mfma_f32_32x32x16_bf16(ah.s, bh1.s, acc1, 0,0,0);
        acc1 = __builtin_amdgcn_mfma_f32_32x32x16_bf16(ah.s, bl1.s, acc1, 0,0,0);
        acc1 = __builtin_amdgcn_mfma_f32_32x32x16_bf16(al.s, bh1.s, acc1, 0,0,0);
    }

    // ---- T -> LDS frag-order (bf16 hi/lo), barrier-protected ----
    __syncthreads();
#pragma unroll
    for (int reg=0; reg<16; reg++){
        int r31o = (reg & 3) + 8*(reg >> 2) + 4*q;
        float v0 = fmaxf(acc0[reg] + bv1a, 0.f);
        float v1 = fmaxf(acc1[reg] + bv1b, 0.f);
        {
            int k = 64*cp + c31;
            int idx = ((rt*8 + (k>>4))*64 + ((k>>3)&1)*32 + r31o)*8 + (k & 7);
            unsigned hb = rne_bf16_hi(v0);
            AhiF[idx] = (unsigned short)(hb >> 16);
            AloF[idx] = (unsigned short)(rne_bf16_hi(v0 - __uint_as_float(hb)) >> 16);
        }
        {
            int k = 64*cp + 32 + c31;
            int idx = ((rt*8 + (k>>4))*64 + ((k>>3)&1)*32 + r31o)*8 + (k & 7);
            unsigned hb = rne_bf16_hi(v1);
            AhiF[idx] = (unsigned short)(hb >> 16);
            AloF[idx] = (unsigned short)(rne_bf16_hi(v1 - __uint_as_float(hb)) >> 16);
        }
    }
    __syncthreads();

    // ---- phase 2: Y = T@W2 + b2 ----
#pragma unroll
    for (int i=0;i<16;i++){ acc0[i]=0.f; acc1[i]=0.f; }
#pragma unroll
    for (int ks=0; ks<8; ks++){
        U4S8 ah, al, bh0, bl0, bh1, bl1;
        ah.u  = *(const uint4*)&AhiF[((rt*8+ks)*64 + lane)*8];
        al.u  = *(const uint4*)&AloF[((rt*8+ks)*64 + lane)*8];
        bh0.u = wf[(((mat2*2+0)*4 + 2*cp+0)*8 + ks)*64 + lane];
        bl0.u = wf[(((mat2*2+1)*4 + 2*cp+0)*8 + ks)*64 + lane];
        bh1.u = wf[(((mat2*2+0)*4 + 2*cp+1)*8 + ks)*64 + lane];
        bl1.u = wf[(((mat2*2+1)*4 + 2*cp+1)*8 + ks)*64 + lane];
        acc0 = __builtin_amdgcn_mfma_f32_32x32x16_bf16(ah.s, bh0.s, acc0, 0,0,0);
        acc0 = __builtin_amdgcn_mfma_f32_32x32x16_bf16(ah.s, bl0.s, acc0, 0,0,0);
        acc0 = __builtin_amdgcn_mfma_f32_32x32x16_bf16(al.s, bh0.s, acc0, 0,0,0);
        acc1 = __builtin_amdgcn_mfma_f32_32x32x16_bf16(ah.s, bh1.s, acc1, 0,0,0);
        acc1 = __builtin_amdgcn_mfma_f32_32x32x16_bf16(ah.s, bl1.s, acc1, 0,0,0);
        acc1 = __builtin_amdgcn_mfma_f32_32x32x16_bf16(al.s, bh1.s, acc1, 0,0,0);
    }

    // ---- epilogue: fp32 + bf16 copy to global ----
#pragma unroll
    for (int reg=0; reg<16; reg++){
        int row = 32*rt + (reg & 3) + 8*(reg >> 2) + 4*q;
        int mm = mb + row;
        if (mm < NN){
            float v0 = acc0[reg] + bv2a;
            float v1 = acc1[reg] + bv2b;
            if (relu2){ v0 = fmaxf(v0, 0.f); v1 = fmaxf(v1, 0.f); }
            xout[(size_t)mm*H + 64*cp      + c31] = v0;
            xout[(size_t)mm*H + 64*cp + 32 + c31] = v1;
            store_xb_pair(xbu, mm, cp, c31, lane, v0, v1);
        }
    }
}

// ---------------- CSR build (by dst) ----------------
__global__ void k_zero(int* p, int n){ int i=blockIdx.x*256+threadIdx.x; if(i<n) p[i]=0; }

__global__ void k_count(const int* __restrict__ ei, int* __restrict__ cnt){
    int e = blockIdx.x*256+threadIdx.x;
    if (e < NE){ int d = ei[NE+e]; if ((unsigned)d < NN) atomicAdd(&cnt[d], 1); }
}

__global__ __launch_bounds__(256) void k_scan1(const int* __restrict__ cnt,
    int* __restrict__ iptr, int* __restrict__ bsum)
{
    __shared__ int s[256];
    int t = threadIdx.x, i = blockIdx.x*256 + t;
    int v = (i < NN) ? cnt[i] : 0;
    s[t] = v;
    for (int off=1; off<256; off<<=1){
        __syncthreads();
        int tv = (t >= off) ? s[t-off] : 0;
        __syncthreads();
        s[t] += tv;
    }
    __syncthreads();
    if (i < NN) iptr[i] = s[t] - v;
    if (t == 255) bsum[blockIdx.x] = s[255];
}

__global__ void k_scan2(int* bsum, int* iptr, int nb){
    if (threadIdx.x==0 && blockIdx.x==0){
        int run = 0;
        for (int b=0;b<nb;b++){ int v=bsum[b]; bsum[b]=run; run+=v; }
        iptr[NN] = run;
    }
}

__global__ void k_scan3(int* __restrict__ iptr, const int* __restrict__ bsum,
                        int* __restrict__ cur)
{
    int i = blockIdx.x*256 + threadIdx.x;
    if (i < NN){ int v = iptr[i] + bsum[i>>8]; iptr[i]=v; cur[i]=v; }
}

__global__ void k_scatter(const int* __restrict__ ei, int* __restrict__ cur,
                          int* __restrict__ esrc)
{
    int e = blockIdx.x*256 + threadIdx.x;
    if (e < NE){
        int d = ei[NE+e];
        if ((unsigned)d < NN){
            int p = atomicAdd(&cur[d], 1);
            if ((unsigned)p < NE) esrc[p] = ei[e];
        }
    }
}

// ---------------- GIN aggregation: wave-per-node, bf16 gather, 8-deep ----------------
// h[i] = x_fp32[i] + sum_j bf16(x[j]); neighbor rows read as packed bf16 (4 B/lane).
__global__ __launch_bounds__(256) void k_agg(const float* __restrict__ x,
    const unsigned* __restrict__ xbu,
    const int* __restrict__ iptr, const int* __restrict__ esrc, float* __restrict__ h)
{
    int node = blockIdx.x*4 + (threadIdx.x >> 6);
    int lane = threadIdx.x & 63;
    int s = __builtin_amdgcn_readfirstlane(iptr[node]);
    int e = __builtin_amdgcn_readfirstlane(iptr[node+1]);
    const float2* __restrict__ xp = (const float2*)x;
    float2 acc = xp[(size_t)node*64 + lane];
    float2 accb = make_float2(0.f, 0.f);
    int j = s;
#define BF2X(u) __uint_as_float((u) << 16)
#define BF2Y(u) __uint_as_float((u) & 0xffff0000u)
    for (; j+8 <= e; j += 8){
        int i0 = esrc[j+0], i1 = esrc[j+1], i2 = esrc[j+2], i3 = esrc[j+3];
        int i4 = esrc[j+4], i5 = esrc[j+5], i6 = esrc[j+6], i7 = esrc[j+7];
        unsigned u0 = xbu[(size_t)i0*64 + lane];
        unsigned u1 = xbu[(size_t)i1*64 + lane];
        unsigned u2 = xbu[(size_t)i2*64 + lane];
        unsigned u3 = xbu[(size_t)i3*64 + lane];
        unsigned u4 = xbu[(size_t)i4*64 + lane];
        unsigned u5 = xbu[(size_t)i5*64 + lane];
        unsigned u6 = xbu[(size_t)i6*64 + lane];
        unsigned u7 = xbu[(size_t)i7*64 + lane];
        acc.x  += (BF2X(u0) + BF2X(u1)) + (BF2X(u2) + BF2X(u3));
        acc.y  += (BF2Y(u0) + BF2Y(u1)) + (BF2Y(u2) + BF2Y(u3));
        accb.x += (BF2X(u4) + BF2X(u5)) + (BF2X(u6) + BF2X(u7));
        accb.y += (BF2Y(u4) + BF2Y(u5)) + (BF2Y(u6) + BF2Y(u7));
    }
    for (; j < e; j++){
        unsigned u = xbu[(size_t)esrc[j]*64 + lane];
        acc.x += BF2X(u); acc.y += BF2Y(u);
    }
#undef BF2X
#undef BF2Y
    acc.x += accb.x; acc.y += accb.y;
    ((float2*)h)[(size_t)node*64 + lane] = acc;
}

// ---------------- per-graph sum pooling ----------------
__global__ __launch_bounds__(128) void k_pool(const float* __restrict__ x,
    const int* __restrict__ batch, float* __restrict__ aggr)
{
    int g = blockIdx.x, c = threadIdx.x;
    int lo=0, hi=NN;
    while (lo<hi){ int mid=(lo+hi)>>1; if (batch[mid] < g) lo=mid+1; else hi=mid; }
    int s0 = lo;
    hi = NN;
    while (lo<hi){ int mid=(lo+hi)>>1; if (batch[mid] < g+1) lo=mid+1; else hi=mid; }
    int e0 = lo;
    float a0=0.f, a1=0.f, a2=0.f, a3=0.f;
    int i = s0;
    for (; i+4 <= e0; i += 4){
        a0 += x[(size_t)(i+0)*H + c];
        a1 += x[(size_t)(i+1)*H + c];
        a2 += x[(size_t)(i+2)*H + c];
        a3 += x[(size_t)(i+3)*H + c];
    }
    for (; i < e0; i++) a0 += x[(size_t)i*H + c];
    aggr[g*H + c] = (a0+a1) + (a2+a3);
}

// ---------------- 4 heads + evidential outputs (FP32 OUTPUT) ----------------
__global__ __launch_bounds__(128) void k_heads(const float* __restrict__ aggr,
    const float* __restrict__ W1, const float* __restrict__ b1,
    const float* __restrict__ W2, const float* __restrict__ b2,
    float* __restrict__ out)
{
    __shared__ float a[H];
    __shared__ float red[H];
    __shared__ float outk[4];
    int g = blockIdx.x, c = threadIdx.x;
    a[c] = aggr[g*H + c];
    __syncthreads();
    for (int k=0;k<4;k++){
        const float* w = W1 + k*H*H;
        float acc = b1[k*H + c];
#pragma unroll 4
        for (int qq=0;qq<H;qq++) acc += a[qq]*w[qq*H + c];
        red[c] = fmaxf(acc, 0.f) * W2[k*H + c];
        __syncthreads();
        for (int sd=64; sd>0; sd>>=1){
            if (c < sd) red[c] += red[c+sd];
            __syncthreads();
        }
        if (c==0) outk[k] = red[0] + b2[k];
        __syncthreads();
    }
    if (c==0){
        float o0=outk[0], o1=outk[1], o2=outk[2], o3=outk[3];
        float alpha = fmaxf(softplusf(o0) + 1.f, 1.f + 1e-4f);
        float beta  = softplusf(o1);
        float nu    = softplusf(o2);
        float am1   = alpha - 1.f;
        float aleat = beta / am1;
        float epis  = beta / (am1 * nu);
        out[0*NG+g] = o3;
        out[1*NG+g] = aleat;
        out[2*NG+g] = epis;
        out[3*NG+g] = nu;
        out[4*NG+g] = alpha;
        out[5*NG+g] = beta;
    }
}

extern "C" void kernel_launch(void* const* d_in, const int* in_sizes, int n_in,
                              void* d_out, int out_size, void* d_ws, size_t ws_size,
                              hipStream_t stream)
{
    const int*   z     = (const int*)d_in[0];
    const float* pos   = (const float*)d_in[1];
    const int*   batch = (const int*)d_in[2];
    const int*   eidx  = (const int*)d_in[3];
    const float* emb   = (const float*)d_in[4];
    const float* Wp    = (const float*)d_in[5];
    const float* bp    = (const float*)d_in[6];
    const float* Wc    = (const float*)d_in[7];
    const float* bc    = (const float*)d_in[8];
    const float* gW1   = (const float*)d_in[9];
    const float* gb1   = (const float*)d_in[10];
    const float* gW2   = (const float*)d_in[11];
    const float* gb2   = (const float*)d_in[12];
    const float* hW1   = (const float*)d_in[13];
    const float* hb1   = (const float*)d_in[14];
    const float* hW2   = (const float*)d_in[15];
    const float* hb2   = (const float*)d_in[16];
    float* out = (float*)d_out;

    bool ok_sizes = (n_in == 17)
        && in_sizes[0] == NN && in_sizes[1] == NN*3 && in_sizes[2] == NN
        && in_sizes[3] == 2*NE && in_sizes[4] == 100*H
        && in_sizes[7] == 2*H*H && in_sizes[9] == 4*H*H
        && in_sizes[13] == 4*H*H && in_sizes[16] == 4;
    if (!ok_sizes){ k_sentinel<<<12, 256, 0, stream>>>(out, 600000.0f); return; }

    const size_t OFF_X    = 256;        // 25,600,000
    const size_t OFF_H    = 25600256;   // 25,600,000
    const size_t OFF_XB   = 51200256;   // 12,800,000 (bf16 copy of x)
    const size_t OFF_AGGR = 64000256;   // 262,144
    const size_t OFF_IPTR = 64262400;   // 200,004
    const size_t OFF_CUR  = 64462464;   // 200,000
    const size_t OFF_ESRC = 64662464;   // 3,200,000
    const size_t OFF_BSUM = 67862464;   // 784
    const size_t OFF_WF   = 67863296;   // 524,288
    const size_t OFF_WCF  = 68387584;   // 131,072
    const size_t REQ      = 68518656;
    if (ws_size < REQ){ k_sentinel<<<12, 256, 0, stream>>>(out, 500000.0f); return; }

    char* ws = (char*)d_ws;
    float*    x    = (float*)(ws + OFF_X);
    float*    h    = (float*)(ws + OFF_H);
    unsigned* xb   = (unsigned*)(ws + OFF_XB);
    float*    aggr = (float*)(ws + OFF_AGGR);
    int*      iptr = (int*)(ws + OFF_IPTR);
    int*      cur  = (int*)(ws + OFF_CUR);
    int*      esrc = (int*)(ws + OFF_ESRC);
    int*      bsum = (int*)(ws + OFF_BSUM);
    uint4*    wf   = (uint4*)(ws + OFF_WF);
    uint4*    wcf  = (uint4*)(ws + OFF_WCF);

    k_wsplit_embed<<<64, 64, 0, stream>>>(Wc, wcf);
    k_embed_mfma<<<(NN+63)/64, 256, 0, stream>>>(z, pos, emb, Wp, bp, bc, wcf, x, xb);

    k_wsplit<<<256, 64, 0, stream>>>(gW1, gW2, wf);

    k_zero<<<(NN+255)/256, 256, 0, stream>>>(cur, NN);
    k_count<<<(NE+255)/256, 256, 0, stream>>>(eidx, cur);
    k_scan1<<<196, 256, 0, stream>>>(cur, iptr, bsum);
    k_scan2<<<1, 64, 0, stream>>>(bsum, iptr, 196);
    k_scan3<<<196, 256, 0, stream>>>(iptr, bsum, cur);
    k_scatter<<<(NE+255)/256, 256, 0, stream>>>(eidx, cur, esrc);

    for (int l=0;l<4;l++){
        k_agg<<<NN/4, 256, 0, stream>>>(x, xb, iptr, esrc, h);
        k_gin_mfma<<<(NN+63)/64, 256, 0, stream>>>(h,
            gb1 + (size_t)l*H, gb2 + (size_t)l*H, wf, x, xb, l, (l<3)?1:0);
    }

    k_pool<<<NG, 128, 0, stream>>>(x, batch, aggr);
    k_heads<<<NG, 128, 0, stream>>>(aggr, hW1, hb1, hW2, hb2, out);
}